// Round 3
// baseline (970.546 us; speedup 1.0000x reference)
//
#include <hip/hip_runtime.h>
#include <math.h>

#define NN 100000
#define EE 640000
#define ENL (EE + NN)
#define HIDD 128

constexpr float BN_EPS = 1e-5f;

// ---------------------------------------------------------------------------
// Tiled fp32 GEMM: out[rows, NC] = A[rows, KDIM] @ W[KDIM, NC]  (+ epilogues)
// EPI 0: + bias            (projection)
// EPI 1: store raw xl, fused a_src/a_dst head reductions (GAT layers)
// EPI 2: + bias, relu, then BN (classifier stage 1)
// Block tile: 64 rows x NC cols, k-tile 32. 256 threads.
// ---------------------------------------------------------------------------
template<int KDIM, int NC, int EPI, int H>
__global__ __launch_bounds__(256) void k_gemm(
    const float* __restrict__ A, const float* __restrict__ W,
    const float* __restrict__ bias, float* __restrict__ out, int nrows,
    const float* __restrict__ att_s, const float* __restrict__ att_d,
    float* __restrict__ a_src, float* __restrict__ a_dst,
    const float* __restrict__ bng, const float* __restrict__ bnb,
    const float* __restrict__ bnm, const float* __restrict__ bnv)
{
    constexpr int TXN = NC / 4;       // thread groups along cols
    constexpr int TYN = 256 / TXN;    // row groups
    constexpr int RPT = 64 / TYN;     // rows per thread
    __shared__ float Al[64][36];      // pad 36: fp32x4-aligned, 2-way bank (free)
    __shared__ float Wl[32][NC];
    const int t = threadIdx.x;
    const int tx = t % TXN, ty = t / TXN;
    const long rowBase = (long)blockIdx.x * 64;
    float acc[RPT][4];
#pragma unroll
    for (int r = 0; r < RPT; ++r) { acc[r][0]=0.f; acc[r][1]=0.f; acc[r][2]=0.f; acc[r][3]=0.f; }

    for (int kk = 0; kk < KDIM; kk += 32) {
        // stage A tile 64x32 (512 float4)
#pragma unroll
        for (int j = 0; j < 2; ++j) {
            int idx = t + j * 256;
            int r = idx >> 3;
            int k4 = (idx & 7) << 2;
            long gr = rowBase + r;
            float4 v = make_float4(0.f, 0.f, 0.f, 0.f);
            if (gr < nrows) v = *(const float4*)(A + gr * KDIM + kk + k4);
            *(float4*)&Al[r][k4] = v;
        }
        // stage W tile 32xNC
        constexpr int WLOAD = (32 * NC / 4) / 256;
#pragma unroll
        for (int j = 0; j < WLOAD; ++j) {
            int idx = t + j * 256;
            int k = idx / TXN;
            int c4 = (idx % TXN) << 2;
            *(float4*)&Wl[k][c4] = *(const float4*)(W + (long)(kk + k) * NC + c4);
        }
        __syncthreads();
#pragma unroll
        for (int k = 0; k < 32; ++k) {
            float4 wv = *(float4*)&Wl[k][tx * 4];
#pragma unroll
            for (int r = 0; r < RPT; ++r) {
                float av = Al[ty * RPT + r][k];
                acc[r][0] = fmaf(av, wv.x, acc[r][0]);
                acc[r][1] = fmaf(av, wv.y, acc[r][1]);
                acc[r][2] = fmaf(av, wv.z, acc[r][2]);
                acc[r][3] = fmaf(av, wv.w, acc[r][3]);
            }
        }
        __syncthreads();
    }

    const int col0 = tx * 4;
    if constexpr (EPI == 0) {
        float4 b4 = *(const float4*)(bias + col0);
#pragma unroll
        for (int r = 0; r < RPT; ++r) {
            long row = rowBase + ty * RPT + r;
            if (row < nrows) {
                float4 o = make_float4(acc[r][0] + b4.x, acc[r][1] + b4.y,
                                       acc[r][2] + b4.z, acc[r][3] + b4.w);
                *(float4*)(out + row * NC + col0) = o;
            }
        }
    } else if constexpr (EPI == 1) {
        float as4[4], ad4[4];
#pragma unroll
        for (int c = 0; c < 4; ++c) { as4[c] = att_s[col0 + c]; ad4[c] = att_d[col0 + c]; }
        constexpr int G = TXN / H;    // lanes per head group
#pragma unroll
        for (int r = 0; r < RPT; ++r) {
            long row = rowBase + ty * RPT + r;
            if (row < nrows) {
                *(float4*)(out + row * NC + col0) =
                    make_float4(acc[r][0], acc[r][1], acc[r][2], acc[r][3]);
            }
            float ps = 0.f, pd = 0.f;
#pragma unroll
            for (int c = 0; c < 4; ++c) {
                ps = fmaf(acc[r][c], as4[c], ps);
                pd = fmaf(acc[r][c], ad4[c], pd);
            }
#pragma unroll
            for (int m_ = 1; m_ < G; m_ <<= 1) {
                ps += __shfl_xor(ps, m_, 64);
                pd += __shfl_xor(pd, m_, 64);
            }
            if ((tx & (G - 1)) == 0 && row < nrows) {
                int h = tx / G;
                a_src[row * H + h] = ps;
                a_dst[row * H + h] = pd;
            }
        }
    } else { // EPI == 2: bias -> relu -> bn
        float4 b4 = *(const float4*)(bias + col0);
        float4 g4 = *(const float4*)(bng + col0);
        float4 be4 = *(const float4*)(bnb + col0);
        float4 m4 = *(const float4*)(bnm + col0);
        float4 v4 = *(const float4*)(bnv + col0);
        float s0 = rsqrtf(v4.x + BN_EPS) * g4.x;
        float s1 = rsqrtf(v4.y + BN_EPS) * g4.y;
        float s2 = rsqrtf(v4.z + BN_EPS) * g4.z;
        float s3 = rsqrtf(v4.w + BN_EPS) * g4.w;
#pragma unroll
        for (int r = 0; r < RPT; ++r) {
            long row = rowBase + ty * RPT + r;
            if (row < nrows) {
                float o0 = fmaxf(acc[r][0] + b4.x, 0.f);
                float o1 = fmaxf(acc[r][1] + b4.y, 0.f);
                float o2 = fmaxf(acc[r][2] + b4.z, 0.f);
                float o3 = fmaxf(acc[r][3] + b4.w, 0.f);
                float4 o = make_float4((o0 - m4.x) * s0 + be4.x,
                                       (o1 - m4.y) * s1 + be4.y,
                                       (o2 - m4.z) * s2 + be4.z,
                                       (o3 - m4.w) * s3 + be4.w);
                *(float4*)(out + row * NC + col0) = o;
            }
        }
    }
}

// ---------------------------------------------------------------------------
// Per-layer tiny prep: Kc[h] = sum_c lin_edge_W[h*C+c]*att_edge[h*C+c]; zero sumfew
// ---------------------------------------------------------------------------
__global__ void k_prep(const float* __restrict__ lew, const float* __restrict__ ae,
                       float* __restrict__ scal, int H)
{
    __shared__ float p[128];
    int t = threadIdx.x;
    p[t] = lew[t] * ae[t];
    __syncthreads();
    if (t == 0) scal[0] = 0.f;
    if (t < H) {
        int Cc = 128 / H;
        float s = 0.f;
        for (int c = 0; c < Cc; ++c) s += p[t * Cc + c];
        scal[4 + t] = s;
    }
}

// ---------------------------------------------------------------------------
// Edge MLP: few[e] = ew * sigmoid( relu(ew*W1+b1) @ W2 + b2 ); also sum(few)
// ---------------------------------------------------------------------------
__global__ __launch_bounds__(256) void k_edgemlp(
    const float* __restrict__ ew, const float* __restrict__ W1,
    const float* __restrict__ b1, const float* __restrict__ W2,
    const float* __restrict__ b2, float* __restrict__ few,
    float* __restrict__ sumfew)
{
    __shared__ float red[4];
    int e = blockIdx.x * 256 + threadIdx.x;
    float f = 0.f;
    if (e < EE) {
        float w = ew[e];
        float acc = b2[0];
#pragma unroll
        for (int j = 0; j < 32; ++j) {
            float t_ = fmaf(w, W1[j], b1[j]);
            t_ = fmaxf(t_, 0.f);
            acc = fmaf(t_, W2[j], acc);
        }
        f = w / (1.f + __expf(-acc));
        few[e] = f;
    }
    float s = f;
#pragma unroll
    for (int m_ = 1; m_ < 64; m_ <<= 1) s += __shfl_xor(s, m_, 64);
    int lane = threadIdx.x & 63, wid = threadIdx.x >> 6;
    if (lane == 0) red[wid] = s;
    __syncthreads();
    if (threadIdx.x == 0) atomicAdd(sumfew, red[0] + red[1] + red[2] + red[3]);
}

// ---------------------------------------------------------------------------
// CSR build: hist -> 2-level exclusive scan -> scatter (bucket by dst)
// ---------------------------------------------------------------------------
__global__ __launch_bounds__(256) void k_hist(const int* __restrict__ edst, int* __restrict__ cnt)
{
    int e = blockIdx.x * 256 + threadIdx.x;
    if (e < ENL) {
        int d = (e < EE) ? edst[e] : (e - EE);
        atomicAdd(&cnt[d], 1);
    }
}

__global__ __launch_bounds__(256) void k_scan1(const int* __restrict__ cnt,
                                               int* __restrict__ tmp, int* __restrict__ part)
{
    __shared__ int s1[256];
    int t = threadIdx.x;
    int i = blockIdx.x * 256 + t;
    int x = (i < NN) ? cnt[i] : 0;
    s1[t] = x;
    __syncthreads();
#pragma unroll
    for (int off = 1; off < 256; off <<= 1) {
        int v_ = (t >= off) ? s1[t - off] : 0;
        __syncthreads();
        s1[t] += v_;
        __syncthreads();
    }
    if (i < NN) tmp[i] = s1[t] - x;
    if (t == 255) part[blockIdx.x] = s1[255];
}

__global__ void k_scan2(int* __restrict__ part, int nb)
{
    __shared__ int s1[512];
    int t = threadIdx.x;
    int x = (t < nb) ? part[t] : 0;
    s1[t] = x;
    __syncthreads();
#pragma unroll
    for (int off = 1; off < 512; off <<= 1) {
        int v_ = (t >= off) ? s1[t - off] : 0;
        __syncthreads();
        s1[t] += v_;
        __syncthreads();
    }
    if (t < nb) part[t] = s1[t] - x;
}

__global__ __launch_bounds__(256) void k_scan3(int* __restrict__ rp, int* __restrict__ cur,
                                               const int* __restrict__ part)
{
    int i = blockIdx.x * 256 + threadIdx.x;
    if (i < NN) {
        int v_ = rp[i] + part[blockIdx.x];
        rp[i] = v_;
        cur[i] = v_;
    } else if (i == NN) {
        rp[NN] = ENL;
    }
}

__global__ __launch_bounds__(256) void k_scatter(const int* __restrict__ edst,
                                                 int* __restrict__ cur, int* __restrict__ eid)
{
    int e = blockIdx.x * 256 + threadIdx.x;
    if (e < ENL) {
        int d = (e < EE) ? edst[e] : (e - EE);
        int pos = atomicAdd(&cur[d], 1);
        eid[pos] = e;
    }
}

// ---------------------------------------------------------------------------
// Per-node GAT softmax + aggregation. One wave per dst node, CSR edge list.
// lane covers cols {lane, lane+64}. Epilogue: +bias, BN, ELU -> hout.
// ---------------------------------------------------------------------------
template<int H>
__global__ __launch_bounds__(256) void k_agg(
    const float* __restrict__ xl, const float* __restrict__ a_src,
    const float* __restrict__ a_dst, const float* __restrict__ few,
    const float* __restrict__ scal, const int* __restrict__ rp,
    const int* __restrict__ eid, const int* __restrict__ esrc,
    const float* __restrict__ bias, const float* __restrict__ bng,
    const float* __restrict__ bnb, const float* __restrict__ bnm,
    const float* __restrict__ bnv, float* __restrict__ hout)
{
    const int lane = threadIdx.x & 63;
    const int n = (blockIdx.x << 2) + (threadIdx.x >> 6);
    if (n >= NN) return;
    const float meanfew = scal[0] * (1.0f / EE);
    float Kc[H], adn[H];
#pragma unroll
    for (int h = 0; h < H; ++h) { Kc[h] = scal[4 + h]; adn[h] = a_dst[n * H + h]; }
    const int p0 = rp[n];
    const int deg = rp[n + 1] - p0;

    // pass 1: per-lane alpha (first chunk cached), running max
    float al[H], mx[H];
#pragma unroll
    for (int h = 0; h < H; ++h) { al[h] = -INFINITY; mx[h] = -INFINITY; }
    for (int base = 0; base < deg; base += 64) {
        int j = base + lane;
        float a_[H];
#pragma unroll
        for (int h = 0; h < H; ++h) a_[h] = -INFINITY;
        if (j < deg) {
            int e = eid[p0 + j];
            int s; float ea;
            if (e < EE) { s = esrc[e]; ea = few[e]; } else { s = e - EE; ea = meanfew; }
#pragma unroll
            for (int h = 0; h < H; ++h) {
                float x_ = a_src[s * H + h] + adn[h] + ea * Kc[h];
                a_[h] = (x_ > 0.f) ? x_ : 0.2f * x_;
            }
        }
        if (base == 0) {
#pragma unroll
            for (int h = 0; h < H; ++h) al[h] = a_[h];
        }
#pragma unroll
        for (int h = 0; h < H; ++h) mx[h] = fmaxf(mx[h], a_[h]);
    }
#pragma unroll
    for (int h = 0; h < H; ++h) {
#pragma unroll
        for (int m_ = 1; m_ < 64; m_ <<= 1) mx[h] = fmaxf(mx[h], __shfl_xor(mx[h], m_, 64));
    }

    // pass 2: denom
    float dn[H];
#pragma unroll
    for (int h = 0; h < H; ++h) dn[h] = 0.f;
    if (deg <= 64) {
#pragma unroll
        for (int h = 0; h < H; ++h) dn[h] = (lane < deg) ? __expf(al[h] - mx[h]) : 0.f;
    } else {
        for (int base = 0; base < deg; base += 64) {
            int j = base + lane;
            if (j < deg) {
                int e = eid[p0 + j];
                int s; float ea;
                if (e < EE) { s = esrc[e]; ea = few[e]; } else { s = e - EE; ea = meanfew; }
#pragma unroll
                for (int h = 0; h < H; ++h) {
                    float x_ = a_src[s * H + h] + adn[h] + ea * Kc[h];
                    x_ = (x_ > 0.f) ? x_ : 0.2f * x_;
                    dn[h] += __expf(x_ - mx[h]);
                }
            }
        }
    }
#pragma unroll
    for (int h = 0; h < H; ++h) {
#pragma unroll
        for (int m_ = 1; m_ < 64; m_ <<= 1) dn[h] += __shfl_xor(dn[h], m_, 64);
        dn[h] = 1.0f / (dn[h] + 1e-16f);
    }

    // pass 3: weighted gather of xl[src]
    float acc0 = 0.f, acc1 = 0.f;
    for (int j = 0; j < deg; ++j) {
        int e = eid[p0 + j];
        int s; float ea;
        if (e < EE) { s = esrc[e]; ea = few[e]; } else { s = e - EE; ea = meanfew; }
        float wA, wB;
        if (deg <= 64) {
            if constexpr (H == 4) {
                float a0 = __shfl(al[0], j, 64);
                float a1 = __shfl(al[1], j, 64);
                float a2 = __shfl(al[2], j, 64);
                float a3 = __shfl(al[3], j, 64);
                float w0 = __expf(a0 - mx[0]) * dn[0];
                float w1 = __expf(a1 - mx[1]) * dn[1];
                float w2 = __expf(a2 - mx[2]) * dn[2];
                float w3 = __expf(a3 - mx[3]) * dn[3];
                wA = (lane < 32) ? w0 : w1;
                wB = (lane < 32) ? w2 : w3;
            } else {
                float a0 = __shfl(al[0], j, 64);
                wA = wB = __expf(a0 - mx[0]) * dn[0];
            }
        } else {
            if constexpr (H == 4) {
                float x0 = a_src[s * 4 + 0] + adn[0] + ea * Kc[0]; x0 = (x0 > 0.f) ? x0 : 0.2f * x0;
                float x1 = a_src[s * 4 + 1] + adn[1] + ea * Kc[1]; x1 = (x1 > 0.f) ? x1 : 0.2f * x1;
                float x2 = a_src[s * 4 + 2] + adn[2] + ea * Kc[2]; x2 = (x2 > 0.f) ? x2 : 0.2f * x2;
                float x3 = a_src[s * 4 + 3] + adn[3] + ea * Kc[3]; x3 = (x3 > 0.f) ? x3 : 0.2f * x3;
                float w0 = __expf(x0 - mx[0]) * dn[0];
                float w1 = __expf(x1 - mx[1]) * dn[1];
                float w2 = __expf(x2 - mx[2]) * dn[2];
                float w3 = __expf(x3 - mx[3]) * dn[3];
                wA = (lane < 32) ? w0 : w1;
                wB = (lane < 32) ? w2 : w3;
            } else {
                float x0 = a_src[s] + adn[0] + ea * Kc[0]; x0 = (x0 > 0.f) ? x0 : 0.2f * x0;
                wA = wB = __expf(x0 - mx[0]) * dn[0];
            }
        }
        const float* xr = xl + (long)s * HIDD;
        acc0 = fmaf(wA, xr[lane], acc0);
        acc1 = fmaf(wB, xr[64 + lane], acc1);
    }

    // epilogue: + gat_bias, BN(eval), ELU
    {
        int c0 = lane, c1 = 64 + lane;
        float o0 = acc0 + bias[c0];
        o0 = (o0 - bnm[c0]) * rsqrtf(bnv[c0] + BN_EPS) * bng[c0] + bnb[c0];
        o0 = (o0 > 0.f) ? o0 : (__expf(o0) - 1.f);
        float o1 = acc1 + bias[c1];
        o1 = (o1 - bnm[c1]) * rsqrtf(bnv[c1] + BN_EPS) * bng[c1] + bnb[c1];
        o1 = (o1 > 0.f) ? o1 : (__expf(o1) - 1.f);
        hout[(long)n * HIDD + c0] = o0;
        hout[(long)n * HIDD + c1] = o1;
    }
}

// ---------------------------------------------------------------------------
// Classifier tail
// ---------------------------------------------------------------------------
__global__ void k_scaleW1(const float* __restrict__ W1, const float* __restrict__ sym,
                          float* __restrict__ W1s)
{
    int i = blockIdx.x * 256 + threadIdx.x;
    if (i < 128 * 64) W1s[i] = W1[i] * sym[i >> 6];
}

__global__ __launch_bounds__(256) void k_clf2(const float* __restrict__ c1,
                                              const float* __restrict__ W2,
                                              const float* __restrict__ b2,
                                              float* __restrict__ c2)
{
    __shared__ float Wl[64][32];
    int t = threadIdx.x;
#pragma unroll
    for (int j = 0; j < 2; ++j) {
        int idx = t + j * 256;
        ((float4*)Wl)[idx] = ((const float4*)W2)[idx];
    }
    __syncthreads();
    int n = blockIdx.x * 256 + t;
    if (n >= NN) return;
    float acc[32];
#pragma unroll
    for (int j = 0; j < 32; ++j) acc[j] = b2[j];
    const float* row = c1 + (long)n * 64;
#pragma unroll
    for (int k0 = 0; k0 < 64; k0 += 4) {
        float4 hv = *(const float4*)(row + k0);
#pragma unroll
        for (int kk = 0; kk < 4; ++kk) {
            float h_ = (&hv.x)[kk];
#pragma unroll
            for (int j4 = 0; j4 < 8; ++j4) {
                float4 w4 = *(float4*)&Wl[k0 + kk][j4 * 4];
                acc[j4 * 4 + 0] = fmaf(h_, w4.x, acc[j4 * 4 + 0]);
                acc[j4 * 4 + 1] = fmaf(h_, w4.y, acc[j4 * 4 + 1]);
                acc[j4 * 4 + 2] = fmaf(h_, w4.z, acc[j4 * 4 + 2]);
                acc[j4 * 4 + 3] = fmaf(h_, w4.w, acc[j4 * 4 + 3]);
            }
        }
    }
    float* o = c2 + (long)n * 32;
#pragma unroll
    for (int j4 = 0; j4 < 8; ++j4) {
        float4 v = make_float4(fmaxf(acc[j4 * 4 + 0], 0.f), fmaxf(acc[j4 * 4 + 1], 0.f),
                               fmaxf(acc[j4 * 4 + 2], 0.f), fmaxf(acc[j4 * 4 + 3], 0.f));
        *(float4*)(o + j4 * 4) = v;
    }
}

__global__ __launch_bounds__(256) void k_clf3(const float* __restrict__ c2,
                                              const float* __restrict__ W3,
                                              const float* __restrict__ b3,
                                              float* __restrict__ out)
{
    int n = blockIdx.x * 256 + threadIdx.x;
    if (n >= NN) return;
    const float* row = c2 + (long)n * 32;
    float l0 = b3[0], l1 = b3[1];
#pragma unroll
    for (int k = 0; k < 32; ++k) {
        float cv = row[k];
        l0 = fmaf(cv, W3[k * 2 + 0], l0);
        l1 = fmaf(cv, W3[k * 2 + 1], l1);
    }
    *(float2*)(out + (long)n * 2) = make_float2(l0, l1);
}

// ---------------------------------------------------------------------------
extern "C" void kernel_launch(void* const* d_in, const int* in_sizes, int n_in,
                              void* d_out, int out_size, void* d_ws, size_t ws_size,
                              hipStream_t stream)
{
    const float* x          = (const float*)d_in[0];
    const int*   edge_index = (const int*)d_in[1];
    const float* edge_w     = (const float*)d_in[2];
    const float* Wproj      = (const float*)d_in[3];
    const float* bproj      = (const float*)d_in[4];
    const float* gat_W      = (const float*)d_in[5];
    const float* att_src    = (const float*)d_in[6];
    const float* att_dst    = (const float*)d_in[7];
    const float* att_edge   = (const float*)d_in[8];
    const float* lin_edge_W = (const float*)d_in[9];
    const float* gat_bias   = (const float*)d_in[10];
    const float* bn_g       = (const float*)d_in[11];
    const float* bn_b       = (const float*)d_in[12];
    const float* bn_m       = (const float*)d_in[13];
    const float* bn_v       = (const float*)d_in[14];
    const float* ew_W1      = (const float*)d_in[15];
    const float* ew_b1      = (const float*)d_in[16];
    const float* ew_W2      = (const float*)d_in[17];
    const float* ew_b2      = (const float*)d_in[18];
    const float* sym        = (const float*)d_in[19];
    const float* clf_W1     = (const float*)d_in[20];
    const float* clf_b1     = (const float*)d_in[21];
    const float* clf_bng    = (const float*)d_in[22];
    const float* clf_bnb    = (const float*)d_in[23];
    const float* clf_bnm    = (const float*)d_in[24];
    const float* clf_bnv    = (const float*)d_in[25];
    const float* clf_W2     = (const float*)d_in[26];
    const float* clf_b2     = (const float*)d_in[27];
    const float* clf_W3     = (const float*)d_in[28];
    const float* clf_b3     = (const float*)d_in[29];
    float* outp = (float*)d_out;

    // workspace layout (floats unless noted); total ~112 MB
    float* ws   = (float*)d_ws;
    float* hbuf = ws;                       // N*128
    float* xl   = hbuf + 12800000;          // N*128 (reused for c1/c2 after layers)
    float* c1   = xl;                       // N*64
    float* c2   = xl + 6400000;             // N*32
    float* asrc = xl + 12800000;            // N*4
    float* adst = asrc + 400000;            // N*4
    float* fewp = adst + 400000;            // E
    float* scal = fewp + 640000;            // [0]=sumfew, [4..7]=Kc
    float* W1s  = scal + 16;                // 128*64
    int* rp   = (int*)(W1s + 8192);         // N+1 (rounded)
    int* cur  = rp + 100004;                // N
    int* eid  = cur + 100000;               // E+N
    int* part = eid + 740000;               // scan partials

    const int* esrc = edge_index;
    const int* edst = edge_index + EE;

    hipMemsetAsync(cur, 0, NN * sizeof(int), stream);

    // input projection: h = x @ Wproj + bproj
    k_gemm<64, 128, 0, 1><<<1563, 256, 0, stream>>>(
        x, Wproj, bproj, hbuf, NN,
        nullptr, nullptr, nullptr, nullptr, nullptr, nullptr, nullptr, nullptr);

    // CSR by dst (graph is layer-invariant)
    k_hist<<<2891, 256, 0, stream>>>(edst, cur);
    k_scan1<<<391, 256, 0, stream>>>(cur, rp, part);
    k_scan2<<<1, 512, 0, stream>>>(part, 391);
    k_scan3<<<391, 256, 0, stream>>>(rp, cur, part);
    k_scatter<<<2891, 256, 0, stream>>>(edst, cur, eid);

    for (int i = 0; i < 3; ++i) {
        int H = (i == 2) ? 1 : 4;
        k_prep<<<1, 128, 0, stream>>>(lin_edge_W + i * 128, att_edge + i * 128, scal, H);
        k_edgemlp<<<2500, 256, 0, stream>>>(edge_w, ew_W1 + i * 32, ew_b1 + i * 32,
                                            ew_W2 + i * 32, ew_b2 + i, fewp, scal);
        if (H == 4) {
            k_gemm<128, 128, 1, 4><<<1563, 256, 0, stream>>>(
                hbuf, gat_W + i * 128 * 128, nullptr, xl, NN,
                att_src + i * 128, att_dst + i * 128, asrc, adst,
                nullptr, nullptr, nullptr, nullptr);
            k_agg<4><<<25000, 256, 0, stream>>>(
                xl, asrc, adst, fewp, scal, rp, eid, esrc,
                gat_bias + i * 128, bn_g + i * 128, bn_b + i * 128,
                bn_m + i * 128, bn_v + i * 128, hbuf);
        } else {
            k_gemm<128, 128, 1, 1><<<1563, 256, 0, stream>>>(
                hbuf, gat_W + i * 128 * 128, nullptr, xl, NN,
                att_src + i * 128, att_dst + i * 128, asrc, adst,
                nullptr, nullptr, nullptr, nullptr);
            k_agg<1><<<25000, 256, 0, stream>>>(
                xl, asrc, adst, fewp, scal, rp, eid, esrc,
                gat_bias + i * 128, bn_g + i * 128, bn_b + i * 128,
                bn_m + i * 128, bn_v + i * 128, hbuf);
        }
    }

    // classifier: fold sym into W1 rows, GEMM+relu+bn, then small dense layers
    k_scaleW1<<<32, 256, 0, stream>>>(clf_W1, sym, W1s);
    k_gemm<128, 64, 2, 1><<<1563, 256, 0, stream>>>(
        hbuf, W1s, clf_b1, c1, NN,
        nullptr, nullptr, nullptr, nullptr, clf_bng, clf_bnb, clf_bnm, clf_bnv);
    k_clf2<<<391, 256, 0, stream>>>(c1, clf_W2, clf_b2, c2);
    k_clf3<<<391, 256, 0, stream>>>(c2, clf_W3, clf_b3, outp);
}

// Round 5
// 913.804 us; speedup vs baseline: 1.0621x; 1.0621x over previous
//
#include <hip/hip_runtime.h>
#include <hip/hip_fp16.h>
#include <math.h>

#define NN 100000
#define EE 640000
#define ENL (EE + NN)
#define HIDD 128

constexpr float BN_EPS = 1e-5f;

// ---------------------------------------------------------------------------
// Tiled fp32 GEMM: out[rows, NC] = A[rows, KDIM] @ W[KDIM, NC]  (+ epilogues)
// EPI 0: + bias, fp32 out                (projection)
// EPI 1: store xl as FP16, fused a_src/a_dst head reductions (GAT layers)
// EPI 2: + bias, relu, then BN, fp32 out (classifier stage 1)
// Block tile: 64 rows x NC cols, k-tile 32. 256 threads.
// ---------------------------------------------------------------------------
template<int KDIM, int NC, int EPI, int H>
__global__ __launch_bounds__(256) void k_gemm(
    const float* __restrict__ A, const float* __restrict__ W,
    const float* __restrict__ bias, float* __restrict__ out, int nrows,
    const float* __restrict__ att_s, const float* __restrict__ att_d,
    float* __restrict__ a_src, float* __restrict__ a_dst,
    const float* __restrict__ bng, const float* __restrict__ bnb,
    const float* __restrict__ bnm, const float* __restrict__ bnv)
{
    constexpr int TXN = NC / 4;       // thread groups along cols
    constexpr int TYN = 256 / TXN;    // row groups
    constexpr int RPT = 64 / TYN;     // rows per thread
    __shared__ float Al[64][36];      // pad 36: fp32x4-aligned, 2-way bank (free)
    __shared__ float Wl[32][NC];
    const int t = threadIdx.x;
    const int tx = t % TXN, ty = t / TXN;
    const long rowBase = (long)blockIdx.x * 64;
    float acc[RPT][4];
#pragma unroll
    for (int r = 0; r < RPT; ++r) { acc[r][0]=0.f; acc[r][1]=0.f; acc[r][2]=0.f; acc[r][3]=0.f; }

    for (int kk = 0; kk < KDIM; kk += 32) {
        // stage A tile 64x32 (512 float4)
#pragma unroll
        for (int j = 0; j < 2; ++j) {
            int idx = t + j * 256;
            int r = idx >> 3;
            int k4 = (idx & 7) << 2;
            long gr = rowBase + r;
            float4 v = make_float4(0.f, 0.f, 0.f, 0.f);
            if (gr < nrows) v = *(const float4*)(A + gr * KDIM + kk + k4);
            *(float4*)&Al[r][k4] = v;
        }
        // stage W tile 32xNC
        constexpr int WLOAD = (32 * NC / 4) / 256;
#pragma unroll
        for (int j = 0; j < WLOAD; ++j) {
            int idx = t + j * 256;
            int k = idx / TXN;
            int c4 = (idx % TXN) << 2;
            *(float4*)&Wl[k][c4] = *(const float4*)(W + (long)(kk + k) * NC + c4);
        }
        __syncthreads();
#pragma unroll
        for (int k = 0; k < 32; ++k) {
            float4 wv = *(float4*)&Wl[k][tx * 4];
#pragma unroll
            for (int r = 0; r < RPT; ++r) {
                float av = Al[ty * RPT + r][k];
                acc[r][0] = fmaf(av, wv.x, acc[r][0]);
                acc[r][1] = fmaf(av, wv.y, acc[r][1]);
                acc[r][2] = fmaf(av, wv.z, acc[r][2]);
                acc[r][3] = fmaf(av, wv.w, acc[r][3]);
            }
        }
        __syncthreads();
    }

    const int col0 = tx * 4;
    if constexpr (EPI == 0) {
        float4 b4 = *(const float4*)(bias + col0);
#pragma unroll
        for (int r = 0; r < RPT; ++r) {
            long row = rowBase + ty * RPT + r;
            if (row < nrows) {
                float4 o = make_float4(acc[r][0] + b4.x, acc[r][1] + b4.y,
                                       acc[r][2] + b4.z, acc[r][3] + b4.w);
                *(float4*)(out + row * NC + col0) = o;
            }
        }
    } else if constexpr (EPI == 1) {
        __half* outh = reinterpret_cast<__half*>(out);
        float as4[4], ad4[4];
#pragma unroll
        for (int c = 0; c < 4; ++c) { as4[c] = att_s[col0 + c]; ad4[c] = att_d[col0 + c]; }
        constexpr int G = TXN / H;    // lanes per head group
#pragma unroll
        for (int r = 0; r < RPT; ++r) {
            long row = rowBase + ty * RPT + r;
            if (row < nrows) {
                union { __half2 h2[2]; uint2 u; } pk;
                pk.h2[0] = __floats2half2_rn(acc[r][0], acc[r][1]);
                pk.h2[1] = __floats2half2_rn(acc[r][2], acc[r][3]);
                *(uint2*)(outh + row * NC + col0) = pk.u;
            }
            float ps = 0.f, pd = 0.f;
#pragma unroll
            for (int c = 0; c < 4; ++c) {
                ps = fmaf(acc[r][c], as4[c], ps);
                pd = fmaf(acc[r][c], ad4[c], pd);
            }
#pragma unroll
            for (int m_ = 1; m_ < G; m_ <<= 1) {
                ps += __shfl_xor(ps, m_, 64);
                pd += __shfl_xor(pd, m_, 64);
            }
            if ((tx & (G - 1)) == 0 && row < nrows) {
                int h = tx / G;
                a_src[row * H + h] = ps;
                a_dst[row * H + h] = pd;
            }
        }
    } else { // EPI == 2: bias -> relu -> bn
        float4 b4 = *(const float4*)(bias + col0);
        float4 g4 = *(const float4*)(bng + col0);
        float4 be4 = *(const float4*)(bnb + col0);
        float4 m4 = *(const float4*)(bnm + col0);
        float4 v4 = *(const float4*)(bnv + col0);
        float s0 = rsqrtf(v4.x + BN_EPS) * g4.x;
        float s1 = rsqrtf(v4.y + BN_EPS) * g4.y;
        float s2 = rsqrtf(v4.z + BN_EPS) * g4.z;
        float s3 = rsqrtf(v4.w + BN_EPS) * g4.w;
#pragma unroll
        for (int r = 0; r < RPT; ++r) {
            long row = rowBase + ty * RPT + r;
            if (row < nrows) {
                float o0 = fmaxf(acc[r][0] + b4.x, 0.f);
                float o1 = fmaxf(acc[r][1] + b4.y, 0.f);
                float o2 = fmaxf(acc[r][2] + b4.z, 0.f);
                float o3 = fmaxf(acc[r][3] + b4.w, 0.f);
                float4 o = make_float4((o0 - m4.x) * s0 + be4.x,
                                       (o1 - m4.y) * s1 + be4.y,
                                       (o2 - m4.z) * s2 + be4.z,
                                       (o3 - m4.w) * s3 + be4.w);
                *(float4*)(out + row * NC + col0) = o;
            }
        }
    }
}

// ---------------------------------------------------------------------------
// Per-layer tiny prep: Kc[h] = sum_c lin_edge_W[h*C+c]*att_edge[h*C+c]; zero sumfew
// ---------------------------------------------------------------------------
__global__ void k_prep(const float* __restrict__ lew, const float* __restrict__ ae,
                       float* __restrict__ scal, int H)
{
    __shared__ float p[128];
    int t = threadIdx.x;
    p[t] = lew[t] * ae[t];
    __syncthreads();
    if (t == 0) scal[0] = 0.f;
    if (t < H) {
        int Cc = 128 / H;
        float s = 0.f;
        for (int c = 0; c < Cc; ++c) s += p[t * Cc + c];
        scal[4 + t] = s;
    }
}

// ---------------------------------------------------------------------------
// Edge MLP: few[e] = ew * sigmoid( relu(ew*W1+b1) @ W2 + b2 ); also sum(few)
// ---------------------------------------------------------------------------
__global__ __launch_bounds__(256) void k_edgemlp(
    const float* __restrict__ ew, const float* __restrict__ W1,
    const float* __restrict__ b1, const float* __restrict__ W2,
    const float* __restrict__ b2, float* __restrict__ few,
    float* __restrict__ sumfew)
{
    __shared__ float red[4];
    int e = blockIdx.x * 256 + threadIdx.x;
    float f = 0.f;
    if (e < EE) {
        float w = ew[e];
        float acc = b2[0];
#pragma unroll
        for (int j = 0; j < 32; ++j) {
            float t_ = fmaf(w, W1[j], b1[j]);
            t_ = fmaxf(t_, 0.f);
            acc = fmaf(t_, W2[j], acc);
        }
        f = w / (1.f + __expf(-acc));
        few[e] = f;
    }
    float s = f;
#pragma unroll
    for (int m_ = 1; m_ < 64; m_ <<= 1) s += __shfl_xor(s, m_, 64);
    int lane = threadIdx.x & 63, wid = threadIdx.x >> 6;
    if (lane == 0) red[wid] = s;
    __syncthreads();
    if (threadIdx.x == 0) atomicAdd(sumfew, red[0] + red[1] + red[2] + red[3]);
}

// ---------------------------------------------------------------------------
// CSR build: hist -> 2-level exclusive scan -> scatter (bucket by dst)
// ---------------------------------------------------------------------------
__global__ __launch_bounds__(256) void k_hist(const int* __restrict__ edst, int* __restrict__ cnt)
{
    int e = blockIdx.x * 256 + threadIdx.x;
    if (e < ENL) {
        int d = (e < EE) ? edst[e] : (e - EE);
        atomicAdd(&cnt[d], 1);
    }
}

__global__ __launch_bounds__(256) void k_scan1(const int* __restrict__ cnt,
                                               int* __restrict__ tmp, int* __restrict__ part)
{
    __shared__ int s1[256];
    int t = threadIdx.x;
    int i = blockIdx.x * 256 + t;
    int x = (i < NN) ? cnt[i] : 0;
    s1[t] = x;
    __syncthreads();
#pragma unroll
    for (int off = 1; off < 256; off <<= 1) {
        int v_ = (t >= off) ? s1[t - off] : 0;
        __syncthreads();
        s1[t] += v_;
        __syncthreads();
    }
    if (i < NN) tmp[i] = s1[t] - x;
    if (t == 255) part[blockIdx.x] = s1[255];
}

__global__ void k_scan2(int* __restrict__ part, int nb)
{
    __shared__ int s1[512];
    int t = threadIdx.x;
    int x = (t < nb) ? part[t] : 0;
    s1[t] = x;
    __syncthreads();
#pragma unroll
    for (int off = 1; off < 512; off <<= 1) {
        int v_ = (t >= off) ? s1[t - off] : 0;
        __syncthreads();
        s1[t] += v_;
        __syncthreads();
    }
    if (t < nb) part[t] = s1[t] - x;
}

__global__ __launch_bounds__(256) void k_scan3(int* __restrict__ rp, int* __restrict__ cur,
                                               const int* __restrict__ part)
{
    int i = blockIdx.x * 256 + threadIdx.x;
    if (i < NN) {
        int v_ = rp[i] + part[blockIdx.x];
        rp[i] = v_;
        cur[i] = v_;
    } else if (i == NN) {
        rp[NN] = ENL;
    }
}

__global__ __launch_bounds__(256) void k_scatter(const int* __restrict__ edst,
                                                 int* __restrict__ cur, int* __restrict__ eid)
{
    int e = blockIdx.x * 256 + threadIdx.x;
    if (e < ENL) {
        int d = (e < EE) ? edst[e] : (e - EE);
        int pos = atomicAdd(&cur[d], 1);
        eid[pos] = e;
    }
}

// ---------------------------------------------------------------------------
// CSR-order permutes: kill the eid indirection in the hot loops.
// ssrc[pos] = src node of CSR slot (once per call);
// sfew[pos] = final edge weight of CSR slot, self-loop mean folded in (per layer)
// ---------------------------------------------------------------------------
__global__ __launch_bounds__(256) void k_psrc(const int* __restrict__ eid,
                                              const int* __restrict__ esrc,
                                              int* __restrict__ ssrc)
{
    int p = blockIdx.x * 256 + threadIdx.x;
    if (p < ENL) {
        int e = eid[p];
        ssrc[p] = (e < EE) ? esrc[e] : (e - EE);
    }
}

__global__ __launch_bounds__(256) void k_pfew(const int* __restrict__ eid,
                                              const float* __restrict__ few,
                                              const float* __restrict__ scal,
                                              float* __restrict__ sfew)
{
    int p = blockIdx.x * 256 + threadIdx.x;
    if (p < ENL) {
        int e = eid[p];
        sfew[p] = (e < EE) ? few[e] : scal[0] * (1.0f / EE);
    }
}

// ---------------------------------------------------------------------------
// Per-node GAT softmax + aggregation. One wave per dst node, CSR edge list.
// xl is FP16; lane covers cols {2*lane, 2*lane+1} (both in head lane>>4 for H=4).
// Epilogue: +bias, BN, ELU -> hout (fp32).
// ---------------------------------------------------------------------------
template<int H>
__global__ __launch_bounds__(256) void k_agg(
    const __half* __restrict__ xl, const float* __restrict__ a_src,
    const float* __restrict__ a_dst, const float* __restrict__ sfew,
    const int* __restrict__ ssrc, const float* __restrict__ scal,
    const int* __restrict__ rp,
    const float* __restrict__ bias, const float* __restrict__ bng,
    const float* __restrict__ bnb, const float* __restrict__ bnm,
    const float* __restrict__ bnv, float* __restrict__ hout)
{
    const int lane = threadIdx.x & 63;
    const int n = (blockIdx.x << 2) + (threadIdx.x >> 6);
    if (n >= NN) return;
    float Kc[H], adn[H];
#pragma unroll
    for (int h = 0; h < H; ++h) { Kc[h] = scal[4 + h]; adn[h] = a_dst[n * H + h]; }
    const int p0 = rp[n];
    const int deg = rp[n + 1] - p0;

    // pass 1: per-lane alpha (first chunk cached), running max
    float al[H], mx[H];
#pragma unroll
    for (int h = 0; h < H; ++h) { al[h] = -INFINITY; mx[h] = -INFINITY; }
    for (int base = 0; base < deg; base += 64) {
        int j = base + lane;
        float a_[H];
#pragma unroll
        for (int h = 0; h < H; ++h) a_[h] = -INFINITY;
        if (j < deg) {
            int s = ssrc[p0 + j];
            float ea = sfew[p0 + j];
            if constexpr (H == 4) {
                float4 as = *(const float4*)(a_src + s * 4);
                float x0 = as.x + adn[0] + ea * Kc[0];
                float x1 = as.y + adn[1] + ea * Kc[1];
                float x2 = as.z + adn[2] + ea * Kc[2];
                float x3 = as.w + adn[3] + ea * Kc[3];
                a_[0] = (x0 > 0.f) ? x0 : 0.2f * x0;
                a_[1] = (x1 > 0.f) ? x1 : 0.2f * x1;
                a_[2] = (x2 > 0.f) ? x2 : 0.2f * x2;
                a_[3] = (x3 > 0.f) ? x3 : 0.2f * x3;
            } else {
                float x0 = a_src[s] + adn[0] + ea * Kc[0];
                a_[0] = (x0 > 0.f) ? x0 : 0.2f * x0;
            }
        }
        if (base == 0) {
#pragma unroll
            for (int h = 0; h < H; ++h) al[h] = a_[h];
        }
#pragma unroll
        for (int h = 0; h < H; ++h) mx[h] = fmaxf(mx[h], a_[h]);
    }
#pragma unroll
    for (int h = 0; h < H; ++h) {
#pragma unroll
        for (int m_ = 1; m_ < 64; m_ <<= 1) mx[h] = fmaxf(mx[h], __shfl_xor(mx[h], m_, 64));
    }

    // pass 2: denom
    float dn[H];
#pragma unroll
    for (int h = 0; h < H; ++h) dn[h] = 0.f;
    if (deg <= 64) {
#pragma unroll
        for (int h = 0; h < H; ++h) dn[h] = (lane < deg) ? __expf(al[h] - mx[h]) : 0.f;
    } else {
        for (int base = 0; base < deg; base += 64) {
            int j = base + lane;
            if (j < deg) {
                int s = ssrc[p0 + j];
                float ea = sfew[p0 + j];
#pragma unroll
                for (int h = 0; h < H; ++h) {
                    float x_ = a_src[s * H + h] + adn[h] + ea * Kc[h];
                    x_ = (x_ > 0.f) ? x_ : 0.2f * x_;
                    dn[h] += __expf(x_ - mx[h]);
                }
            }
        }
    }
#pragma unroll
    for (int h = 0; h < H; ++h) {
#pragma unroll
        for (int m_ = 1; m_ < 64; m_ <<= 1) dn[h] += __shfl_xor(dn[h], m_, 64);
        dn[h] = 1.0f / (dn[h] + 1e-16f);
    }

    // pass 3: weighted gather of fp16 xl[src]; lane holds cols 2*lane, 2*lane+1
    float acc0 = 0.f, acc1 = 0.f;
    for (int j = 0; j < deg; ++j) {
        int s = ssrc[p0 + j];          // uniform (L1-hot after pass 1)
        float wsel;
        if (deg <= 64) {
            if constexpr (H == 4) {
                float a0 = __shfl(al[0], j, 64);
                float a1 = __shfl(al[1], j, 64);
                float a2 = __shfl(al[2], j, 64);
                float a3 = __shfl(al[3], j, 64);
                float w0 = __expf(a0 - mx[0]) * dn[0];
                float w1 = __expf(a1 - mx[1]) * dn[1];
                float w2 = __expf(a2 - mx[2]) * dn[2];
                float w3 = __expf(a3 - mx[3]) * dn[3];
                wsel = (lane < 16) ? w0 : ((lane < 32) ? w1 : ((lane < 48) ? w2 : w3));
            } else {
                float a0 = __shfl(al[0], j, 64);
                wsel = __expf(a0 - mx[0]) * dn[0];
            }
        } else {
            float ea = sfew[p0 + j];
            if constexpr (H == 4) {
                float4 as = *(const float4*)(a_src + s * 4);
                float x0 = as.x + adn[0] + ea * Kc[0]; x0 = (x0 > 0.f) ? x0 : 0.2f * x0;
                float x1 = as.y + adn[1] + ea * Kc[1]; x1 = (x1 > 0.f) ? x1 : 0.2f * x1;
                float x2 = as.z + adn[2] + ea * Kc[2]; x2 = (x2 > 0.f) ? x2 : 0.2f * x2;
                float x3 = as.w + adn[3] + ea * Kc[3]; x3 = (x3 > 0.f) ? x3 : 0.2f * x3;
                float w0 = __expf(x0 - mx[0]) * dn[0];
                float w1 = __expf(x1 - mx[1]) * dn[1];
                float w2 = __expf(x2 - mx[2]) * dn[2];
                float w3 = __expf(x3 - mx[3]) * dn[3];
                wsel = (lane < 16) ? w0 : ((lane < 32) ? w1 : ((lane < 48) ? w2 : w3));
            } else {
                float x0 = a_src[s] + adn[0] + ea * Kc[0]; x0 = (x0 > 0.f) ? x0 : 0.2f * x0;
                wsel = __expf(x0 - mx[0]) * dn[0];
            }
        }
        const __half2* xr = (const __half2*)(xl + (size_t)s * HIDD);
        float2 f = __half22float2(xr[lane]);
        acc0 = fmaf(wsel, f.x, acc0);
        acc1 = fmaf(wsel, f.y, acc1);
    }

    // epilogue: + gat_bias, BN(eval), ELU; cols c0=2*lane, c0+1
    {
        int c0 = 2 * lane;
        float2 bi = *(const float2*)(bias + c0);
        float2 g  = *(const float2*)(bng + c0);
        float2 bb = *(const float2*)(bnb + c0);
        float2 mm = *(const float2*)(bnm + c0);
        float2 vv = *(const float2*)(bnv + c0);
        float o0 = acc0 + bi.x;
        o0 = (o0 - mm.x) * rsqrtf(vv.x + BN_EPS) * g.x + bb.x;
        o0 = (o0 > 0.f) ? o0 : (__expf(o0) - 1.f);
        float o1 = acc1 + bi.y;
        o1 = (o1 - mm.y) * rsqrtf(vv.y + BN_EPS) * g.y + bb.y;
        o1 = (o1 > 0.f) ? o1 : (__expf(o1) - 1.f);
        *(float2*)(hout + (size_t)n * HIDD + c0) = make_float2(o0, o1);
    }
}

// ---------------------------------------------------------------------------
// Classifier tail
// ---------------------------------------------------------------------------
__global__ void k_scaleW1(const float* __restrict__ W1, const float* __restrict__ sym,
                          float* __restrict__ W1s)
{
    int i = blockIdx.x * 256 + threadIdx.x;
    if (i < 128 * 64) W1s[i] = W1[i] * sym[i >> 6];
}

__global__ __launch_bounds__(256) void k_clf2(const float* __restrict__ c1,
                                              const float* __restrict__ W2,
                                              const float* __restrict__ b2,
                                              float* __restrict__ c2)
{
    __shared__ float Wl[64][32];
    int t = threadIdx.x;
#pragma unroll
    for (int j = 0; j < 2; ++j) {
        int idx = t + j * 256;
        ((float4*)Wl)[idx] = ((const float4*)W2)[idx];
    }
    __syncthreads();
    int n = blockIdx.x * 256 + t;
    if (n >= NN) return;
    float acc[32];
#pragma unroll
    for (int j = 0; j < 32; ++j) acc[j] = b2[j];
    const float* row = c1 + (long)n * 64;
#pragma unroll
    for (int k0 = 0; k0 < 64; k0 += 4) {
        float4 hv = *(const float4*)(row + k0);
#pragma unroll
        for (int kk = 0; kk < 4; ++kk) {
            float h_ = (&hv.x)[kk];
#pragma unroll
            for (int j4 = 0; j4 < 8; ++j4) {
                float4 w4 = *(float4*)&Wl[k0 + kk][j4 * 4];
                acc[j4 * 4 + 0] = fmaf(h_, w4.x, acc[j4 * 4 + 0]);
                acc[j4 * 4 + 1] = fmaf(h_, w4.y, acc[j4 * 4 + 1]);
                acc[j4 * 4 + 2] = fmaf(h_, w4.z, acc[j4 * 4 + 2]);
                acc[j4 * 4 + 3] = fmaf(h_, w4.w, acc[j4 * 4 + 3]);
            }
        }
    }
    float* o = c2 + (long)n * 32;
#pragma unroll
    for (int j4 = 0; j4 < 8; ++j4) {
        float4 v = make_float4(fmaxf(acc[j4 * 4 + 0], 0.f), fmaxf(acc[j4 * 4 + 1], 0.f),
                               fmaxf(acc[j4 * 4 + 2], 0.f), fmaxf(acc[j4 * 4 + 3], 0.f));
        *(float4*)(o + j4 * 4) = v;
    }
}

__global__ __launch_bounds__(256) void k_clf3(const float* __restrict__ c2,
                                              const float* __restrict__ W3,
                                              const float* __restrict__ b3,
                                              float* __restrict__ out)
{
    int n = blockIdx.x * 256 + threadIdx.x;
    if (n >= NN) return;
    const float* row = c2 + (long)n * 32;
    float l0 = b3[0], l1 = b3[1];
#pragma unroll
    for (int k = 0; k < 32; ++k) {
        float cv = row[k];
        l0 = fmaf(cv, W3[k * 2 + 0], l0);
        l1 = fmaf(cv, W3[k * 2 + 1], l1);
    }
    *(float2*)(out + (long)n * 2) = make_float2(l0, l1);
}

// ---------------------------------------------------------------------------
extern "C" void kernel_launch(void* const* d_in, const int* in_sizes, int n_in,
                              void* d_out, int out_size, void* d_ws, size_t ws_size,
                              hipStream_t stream)
{
    const float* x          = (const float*)d_in[0];
    const int*   edge_index = (const int*)d_in[1];
    const float* edge_w     = (const float*)d_in[2];
    const float* Wproj      = (const float*)d_in[3];
    const float* bproj      = (const float*)d_in[4];
    const float* gat_W      = (const float*)d_in[5];
    const float* att_src    = (const float*)d_in[6];
    const float* att_dst    = (const float*)d_in[7];
    const float* att_edge   = (const float*)d_in[8];
    const float* lin_edge_W = (const float*)d_in[9];
    const float* gat_bias   = (const float*)d_in[10];
    const float* bn_g       = (const float*)d_in[11];
    const float* bn_b       = (const float*)d_in[12];
    const float* bn_m       = (const float*)d_in[13];
    const float* bn_v       = (const float*)d_in[14];
    const float* ew_W1      = (const float*)d_in[15];
    const float* ew_b1      = (const float*)d_in[16];
    const float* ew_W2      = (const float*)d_in[17];
    const float* ew_b2      = (const float*)d_in[18];
    const float* sym        = (const float*)d_in[19];
    const float* clf_W1     = (const float*)d_in[20];
    const float* clf_b1     = (const float*)d_in[21];
    const float* clf_bng    = (const float*)d_in[22];
    const float* clf_bnb    = (const float*)d_in[23];
    const float* clf_bnm    = (const float*)d_in[24];
    const float* clf_bnv    = (const float*)d_in[25];
    const float* clf_W2     = (const float*)d_in[26];
    const float* clf_b2     = (const float*)d_in[27];
    const float* clf_W3     = (const float*)d_in[28];
    const float* clf_b3     = (const float*)d_in[29];
    float* outp = (float*)d_out;

    // workspace layout (float slots); total ~112 MB (fits: round-3 run passed)
    float* ws   = (float*)d_ws;
    float* hbuf = ws;                       // N*128 fp32
    float* xlf  = hbuf + 12800000;          // region of 12.8M float slots
    __half* xl  = (__half*)xlf;             // N*128 fp16 = first 6.4M float slots
    float* c1   = xlf;                      // N*64 fp32 (clf stage, after layers)
    int*   ssrc = (int*)(xlf + 6400000);    // ENL ints (aliases c2's region, disjoint in time)
    float* sfew = xlf + 7200000;            // ENL floats
    float* c2   = xlf + 6400000;            // N*32 fp32 (after last k_agg/ssrc use)
    float* asrc = xlf + 12800000;           // N*4
    float* adst = asrc + 400000;            // N*4
    float* fewp = adst + 400000;            // E
    float* scal = fewp + 640000;            // [0]=sumfew, [4..7]=Kc
    float* W1s  = scal + 16;                // 128*64
    int* rp   = (int*)(W1s + 8192);         // N+1 (rounded)
    int* cur  = rp + 100004;                // N
    int* eid  = cur + 100000;               // E+N
    int* part = eid + 740000;               // scan partials

    const int* esrc = edge_index;
    const int* edst = edge_index + EE;

    hipMemsetAsync(cur, 0, NN * sizeof(int), stream);

    // input projection: h = x @ Wproj + bproj
    k_gemm<64, 128, 0, 1><<<1563, 256, 0, stream>>>(
        x, Wproj, bproj, hbuf, NN,
        nullptr, nullptr, nullptr, nullptr, nullptr, nullptr, nullptr, nullptr);

    // CSR by dst (graph is layer-invariant) + CSR-order src permute
    k_hist<<<2891, 256, 0, stream>>>(edst, cur);
    k_scan1<<<391, 256, 0, stream>>>(cur, rp, part);
    k_scan2<<<1, 512, 0, stream>>>(part, 391);
    k_scan3<<<391, 256, 0, stream>>>(rp, cur, part);
    k_scatter<<<2891, 256, 0, stream>>>(edst, cur, eid);
    k_psrc<<<2891, 256, 0, stream>>>(eid, esrc, ssrc);

    for (int i = 0; i < 3; ++i) {
        int H = (i == 2) ? 1 : 4;
        k_prep<<<1, 128, 0, stream>>>(lin_edge_W + i * 128, att_edge + i * 128, scal, H);
        k_edgemlp<<<2500, 256, 0, stream>>>(edge_w, ew_W1 + i * 32, ew_b1 + i * 32,
                                            ew_W2 + i * 32, ew_b2 + i, fewp, scal);
        k_pfew<<<2891, 256, 0, stream>>>(eid, fewp, scal, sfew);
        if (H == 4) {
            k_gemm<128, 128, 1, 4><<<1563, 256, 0, stream>>>(
                hbuf, gat_W + i * 128 * 128, nullptr, xlf, NN,
                att_src + i * 128, att_dst + i * 128, asrc, adst,
                nullptr, nullptr, nullptr, nullptr);
            k_agg<4><<<25000, 256, 0, stream>>>(
                xl, asrc, adst, sfew, ssrc, scal, rp,
                gat_bias + i * 128, bn_g + i * 128, bn_b + i * 128,
                bn_m + i * 128, bn_v + i * 128, hbuf);
        } else {
            k_gemm<128, 128, 1, 1><<<1563, 256, 0, stream>>>(
                hbuf, gat_W + i * 128 * 128, nullptr, xlf, NN,
                att_src + i * 128, att_dst + i * 128, asrc, adst,
                nullptr, nullptr, nullptr, nullptr);
            k_agg<1><<<25000, 256, 0, stream>>>(
                xl, asrc, adst, sfew, ssrc, scal, rp,
                gat_bias + i * 128, bn_g + i * 128, bn_b + i * 128,
                bn_m + i * 128, bn_v + i * 128, hbuf);
        }
    }

    // classifier: fold sym into W1 rows, GEMM+relu+bn, then small dense layers
    k_scaleW1<<<32, 256, 0, stream>>>(clf_W1, sym, W1s);
    k_gemm<128, 64, 2, 1><<<1563, 256, 0, stream>>>(
        hbuf, W1s, clf_b1, c1, NN,
        nullptr, nullptr, nullptr, nullptr, clf_bng, clf_bnb, clf_bnm, clf_bnv);
    k_clf2<<<391, 256, 0, stream>>>(c1, clf_W2, clf_b2, c2);
    k_clf3<<<391, 256, 0, stream>>>(c2, clf_W3, clf_b3, outp);
}

// Round 10
// 784.179 us; speedup vs baseline: 1.2377x; 1.1653x over previous
//
#include <hip/hip_runtime.h>
#include <hip/hip_fp16.h>
#include <math.h>

#define NN 100000
#define EE 640000
#define ENL (EE + NN)
#define HIDD 128

constexpr float BN_EPS = 1e-5f;

// ---------------------------------------------------------------------------
// Tiled fp32 GEMM: out[rows, NC] = A[rows, KDIM] @ W[KDIM, NC]  (+ epilogues)
// EPI 0: + bias, fp32 out                (projection)
// EPI 1: store xl as FP16, fused a_src/a_dst head reductions (GAT layers)
// EPI 2: + bias, relu, then BN, fp32 out (classifier stage 1)
// Block tile: 64 rows x NC cols, k-tile 32. 256 threads.
// ---------------------------------------------------------------------------
template<int KDIM, int NC, int EPI, int H>
__global__ __launch_bounds__(256) void k_gemm(
    const float* __restrict__ A, const float* __restrict__ W,
    const float* __restrict__ bias, float* __restrict__ out, int nrows,
    const float* __restrict__ att_s, const float* __restrict__ att_d,
    float* __restrict__ a_src, float* __restrict__ a_dst,
    const float* __restrict__ bng, const float* __restrict__ bnb,
    const float* __restrict__ bnm, const float* __restrict__ bnv)
{
    constexpr int TXN = NC / 4;       // thread groups along cols
    constexpr int TYN = 256 / TXN;    // row groups
    constexpr int RPT = 64 / TYN;     // rows per thread
    __shared__ float Al[64][36];      // pad 36: fp32x4-aligned, 2-way bank (free)
    __shared__ float Wl[32][NC];
    const int t = threadIdx.x;
    const int tx = t % TXN, ty = t / TXN;
    const long rowBase = (long)blockIdx.x * 64;
    float acc[RPT][4];
#pragma unroll
    for (int r = 0; r < RPT; ++r) { acc[r][0]=0.f; acc[r][1]=0.f; acc[r][2]=0.f; acc[r][3]=0.f; }

    for (int kk = 0; kk < KDIM; kk += 32) {
        // stage A tile 64x32 (512 float4)
#pragma unroll
        for (int j = 0; j < 2; ++j) {
            int idx = t + j * 256;
            int r = idx >> 3;
            int k4 = (idx & 7) << 2;
            long gr = rowBase + r;
            float4 v = make_float4(0.f, 0.f, 0.f, 0.f);
            if (gr < nrows) v = *(const float4*)(A + gr * KDIM + kk + k4);
            *(float4*)&Al[r][k4] = v;
        }
        // stage W tile 32xNC
        constexpr int WLOAD = (32 * NC / 4) / 256;
#pragma unroll
        for (int j = 0; j < WLOAD; ++j) {
            int idx = t + j * 256;
            int k = idx / TXN;
            int c4 = (idx % TXN) << 2;
            *(float4*)&Wl[k][c4] = *(const float4*)(W + (long)(kk + k) * NC + c4);
        }
        __syncthreads();
#pragma unroll
        for (int k = 0; k < 32; ++k) {
            float4 wv = *(float4*)&Wl[k][tx * 4];
#pragma unroll
            for (int r = 0; r < RPT; ++r) {
                float av = Al[ty * RPT + r][k];
                acc[r][0] = fmaf(av, wv.x, acc[r][0]);
                acc[r][1] = fmaf(av, wv.y, acc[r][1]);
                acc[r][2] = fmaf(av, wv.z, acc[r][2]);
                acc[r][3] = fmaf(av, wv.w, acc[r][3]);
            }
        }
        __syncthreads();
    }

    const int col0 = tx * 4;
    if constexpr (EPI == 0) {
        float4 b4 = *(const float4*)(bias + col0);
#pragma unroll
        for (int r = 0; r < RPT; ++r) {
            long row = rowBase + ty * RPT + r;
            if (row < nrows) {
                float4 o = make_float4(acc[r][0] + b4.x, acc[r][1] + b4.y,
                                       acc[r][2] + b4.z, acc[r][3] + b4.w);
                *(float4*)(out + row * NC + col0) = o;
            }
        }
    } else if constexpr (EPI == 1) {
        __half* outh = reinterpret_cast<__half*>(out);
        float as4[4], ad4[4];
#pragma unroll
        for (int c = 0; c < 4; ++c) { as4[c] = att_s[col0 + c]; ad4[c] = att_d[col0 + c]; }
        constexpr int G = TXN / H;    // lanes per head group
#pragma unroll
        for (int r = 0; r < RPT; ++r) {
            long row = rowBase + ty * RPT + r;
            if (row < nrows) {
                union { __half2 h2[2]; uint2 u; } pk;
                pk.h2[0] = __floats2half2_rn(acc[r][0], acc[r][1]);
                pk.h2[1] = __floats2half2_rn(acc[r][2], acc[r][3]);
                *(uint2*)(outh + row * NC + col0) = pk.u;
            }
            float ps = 0.f, pd = 0.f;
#pragma unroll
            for (int c = 0; c < 4; ++c) {
                ps = fmaf(acc[r][c], as4[c], ps);
                pd = fmaf(acc[r][c], ad4[c], pd);
            }
#pragma unroll
            for (int m_ = 1; m_ < G; m_ <<= 1) {
                ps += __shfl_xor(ps, m_, 64);
                pd += __shfl_xor(pd, m_, 64);
            }
            if ((tx & (G - 1)) == 0 && row < nrows) {
                int h = tx / G;
                a_src[row * H + h] = ps;
                a_dst[row * H + h] = pd;
            }
        }
    } else { // EPI == 2: bias -> relu -> bn
        float4 b4 = *(const float4*)(bias + col0);
        float4 g4 = *(const float4*)(bng + col0);
        float4 be4 = *(const float4*)(bnb + col0);
        float4 m4 = *(const float4*)(bnm + col0);
        float4 v4 = *(const float4*)(bnv + col0);
        float s0 = rsqrtf(v4.x + BN_EPS) * g4.x;
        float s1 = rsqrtf(v4.y + BN_EPS) * g4.y;
        float s2 = rsqrtf(v4.z + BN_EPS) * g4.z;
        float s3 = rsqrtf(v4.w + BN_EPS) * g4.w;
#pragma unroll
        for (int r = 0; r < RPT; ++r) {
            long row = rowBase + ty * RPT + r;
            if (row < nrows) {
                float o0 = fmaxf(acc[r][0] + b4.x, 0.f);
                float o1 = fmaxf(acc[r][1] + b4.y, 0.f);
                float o2 = fmaxf(acc[r][2] + b4.z, 0.f);
                float o3 = fmaxf(acc[r][3] + b4.w, 0.f);
                float4 o = make_float4((o0 - m4.x) * s0 + be4.x,
                                       (o1 - m4.y) * s1 + be4.y,
                                       (o2 - m4.z) * s2 + be4.z,
                                       (o3 - m4.w) * s3 + be4.w);
                *(float4*)(out + row * NC + col0) = o;
            }
        }
    }
}

// ---------------------------------------------------------------------------
// Per-layer tiny prep: Kc[h] = sum_c lin_edge_W[h*C+c]*att_edge[h*C+c]; zero sumfew
// ---------------------------------------------------------------------------
__global__ void k_prep(const float* __restrict__ lew, const float* __restrict__ ae,
                       float* __restrict__ scal, int H)
{
    __shared__ float p[128];
    int t = threadIdx.x;
    p[t] = lew[t] * ae[t];
    __syncthreads();
    if (t == 0) scal[0] = 0.f;
    if (t < H) {
        int Cc = 128 / H;
        float s = 0.f;
        for (int c = 0; c < Cc; ++c) s += p[t * Cc + c];
        scal[4 + t] = s;
    }
}

// ---------------------------------------------------------------------------
// Edge MLP: few[e] = ew * sigmoid( relu(ew*W1+b1) @ W2 + b2 ); also sum(few)
// ---------------------------------------------------------------------------
__global__ __launch_bounds__(256) void k_edgemlp(
    const float* __restrict__ ew, const float* __restrict__ W1,
    const float* __restrict__ b1, const float* __restrict__ W2,
    const float* __restrict__ b2, float* __restrict__ few,
    float* __restrict__ sumfew)
{
    __shared__ float red[4];
    int e = blockIdx.x * 256 + threadIdx.x;
    float f = 0.f;
    if (e < EE) {
        float w = ew[e];
        float acc = b2[0];
#pragma unroll
        for (int j = 0; j < 32; ++j) {
            float t_ = fmaf(w, W1[j], b1[j]);
            t_ = fmaxf(t_, 0.f);
            acc = fmaf(t_, W2[j], acc);
        }
        f = w / (1.f + __expf(-acc));
        few[e] = f;
    }
    float s = f;
#pragma unroll
    for (int m_ = 1; m_ < 64; m_ <<= 1) s += __shfl_xor(s, m_, 64);
    int lane = threadIdx.x & 63, wid = threadIdx.x >> 6;
    if (lane == 0) red[wid] = s;
    __syncthreads();
    if (threadIdx.x == 0) atomicAdd(sumfew, red[0] + red[1] + red[2] + red[3]);
}

// ---------------------------------------------------------------------------
// CSR build: hist -> 2-level exclusive scan -> scatter (bucket by dst)
// ---------------------------------------------------------------------------
__global__ __launch_bounds__(256) void k_hist(const int* __restrict__ edst, int* __restrict__ cnt)
{
    int e = blockIdx.x * 256 + threadIdx.x;
    if (e < ENL) {
        int d = (e < EE) ? edst[e] : (e - EE);
        atomicAdd(&cnt[d], 1);
    }
}

__global__ __launch_bounds__(256) void k_scan1(const int* __restrict__ cnt,
                                               int* __restrict__ tmp, int* __restrict__ part)
{
    __shared__ int s1[256];
    int t = threadIdx.x;
    int i = blockIdx.x * 256 + t;
    int x = (i < NN) ? cnt[i] : 0;
    s1[t] = x;
    __syncthreads();
#pragma unroll
    for (int off = 1; off < 256; off <<= 1) {
        int v_ = (t >= off) ? s1[t - off] : 0;
        __syncthreads();
        s1[t] += v_;
        __syncthreads();
    }
    if (i < NN) tmp[i] = s1[t] - x;
    if (t == 255) part[blockIdx.x] = s1[255];
}

__global__ void k_scan2(int* __restrict__ part, int nb)
{
    __shared__ int s1[512];
    int t = threadIdx.x;
    int x = (t < nb) ? part[t] : 0;
    s1[t] = x;
    __syncthreads();
#pragma unroll
    for (int off = 1; off < 512; off <<= 1) {
        int v_ = (t >= off) ? s1[t - off] : 0;
        __syncthreads();
        s1[t] += v_;
        __syncthreads();
    }
    if (t < nb) part[t] = s1[t] - x;
}

__global__ __launch_bounds__(256) void k_scan3(int* __restrict__ rp, int* __restrict__ cur,
                                               const int* __restrict__ part)
{
    int i = blockIdx.x * 256 + threadIdx.x;
    if (i < NN) {
        int v_ = rp[i] + part[blockIdx.x];
        rp[i] = v_;
        cur[i] = v_;
    } else if (i == NN) {
        rp[NN] = ENL;
    }
}

__global__ __launch_bounds__(256) void k_scatter(const int* __restrict__ edst,
                                                 int* __restrict__ cur, int* __restrict__ eid)
{
    int e = blockIdx.x * 256 + threadIdx.x;
    if (e < ENL) {
        int d = (e < EE) ? edst[e] : (e - EE);
        int pos = atomicAdd(&cur[d], 1);
        eid[pos] = e;
    }
}

// ---------------------------------------------------------------------------
// CSR-order permutes: kill the eid indirection in the hot loops.
// ---------------------------------------------------------------------------
__global__ __launch_bounds__(256) void k_psrc(const int* __restrict__ eid,
                                              const int* __restrict__ esrc,
                                              int* __restrict__ ssrc)
{
    int p = blockIdx.x * 256 + threadIdx.x;
    if (p < ENL) {
        int e = eid[p];
        ssrc[p] = (e < EE) ? esrc[e] : (e - EE);
    }
}

__global__ __launch_bounds__(256) void k_pfew(const int* __restrict__ eid,
                                              const float* __restrict__ few,
                                              const float* __restrict__ scal,
                                              float* __restrict__ sfew)
{
    int p = blockIdx.x * 256 + threadIdx.x;
    if (p < ENL) {
        int e = eid[p];
        sfew[p] = (e < EE) ? few[e] : scal[0] * (1.0f / EE);
    }
}

// ---------------------------------------------------------------------------
// Per-node GAT softmax + aggregation. One wave per dst node, CSR edge list.
// Fast path (deg<=64): exp computed ONCE per lane; normalized weights staged
// in LDS (pad 66 -> conflict-free broadcast); gather unrolled x4 for MLP.
// Slow path (deg>64, ~never): recompute 3-pass. One barrier reached by ALL.
// xl is FP16; lane covers cols {2*lane, 2*lane+1}; head = lane>>4 for H=4.
// ---------------------------------------------------------------------------
template<int H>
__global__ __launch_bounds__(256) void k_agg(
    const __half* __restrict__ xl, const float* __restrict__ a_src,
    const float* __restrict__ a_dst, const float* __restrict__ sfew,
    const int* __restrict__ ssrc, const float* __restrict__ scal,
    const int* __restrict__ rp,
    const float* __restrict__ bias, const float* __restrict__ bng,
    const float* __restrict__ bnb, const float* __restrict__ bnm,
    const float* __restrict__ bnv, float* __restrict__ hout)
{
    __shared__ float lw[4][H][66];
    const int lane = threadIdx.x & 63;
    const int wid  = threadIdx.x >> 6;
    const int n = (blockIdx.x << 2) + wid;   // grid = 25000*4 == NN exactly
    float Kc[H], adn[H];
#pragma unroll
    for (int h = 0; h < H; ++h) { Kc[h] = scal[4 + h]; adn[h] = a_dst[n * H + h]; }
    const int p0 = rp[n];
    const int deg = rp[n + 1] - p0;
    const bool fast = (deg <= 64);

    float acc0 = 0.f, acc1 = 0.f;

    if (fast) {
        const bool act = lane < deg;
        float al[H];
        if (act) {
            int s = ssrc[p0 + lane];
            float ea = sfew[p0 + lane];
            if constexpr (H == 4) {
                float4 as = *(const float4*)(a_src + s * 4);
                float x0 = as.x + adn[0] + ea * Kc[0];
                float x1 = as.y + adn[1] + ea * Kc[1];
                float x2 = as.z + adn[2] + ea * Kc[2];
                float x3 = as.w + adn[3] + ea * Kc[3];
                al[0] = (x0 > 0.f) ? x0 : 0.2f * x0;
                al[1] = (x1 > 0.f) ? x1 : 0.2f * x1;
                al[2] = (x2 > 0.f) ? x2 : 0.2f * x2;
                al[3] = (x3 > 0.f) ? x3 : 0.2f * x3;
            } else {
                float x0 = a_src[s] + adn[0] + ea * Kc[0];
                al[0] = (x0 > 0.f) ? x0 : 0.2f * x0;
            }
        } else {
#pragma unroll
            for (int h = 0; h < H; ++h) al[h] = -INFINITY;
        }
        float mx[H], ex[H], dn[H];
#pragma unroll
        for (int h = 0; h < H; ++h) {
            mx[h] = al[h];
#pragma unroll
            for (int m_ = 1; m_ < 64; m_ <<= 1) mx[h] = fmaxf(mx[h], __shfl_xor(mx[h], m_, 64));
        }
#pragma unroll
        for (int h = 0; h < H; ++h) {
            ex[h] = act ? __expf(al[h] - mx[h]) : 0.f;
            dn[h] = ex[h];
#pragma unroll
            for (int m_ = 1; m_ < 64; m_ <<= 1) dn[h] += __shfl_xor(dn[h], m_, 64);
            lw[wid][h][lane] = ex[h] * (1.0f / (dn[h] + 1e-16f));
        }
    }
    __syncthreads();   // single barrier, reached by every wave exactly once

    if (fast) {
        const int myh = (H == 4) ? (lane >> 4) : 0;
        const float* wrow = &lw[wid][myh][0];
        int j = 0;
        for (; j + 4 <= deg; j += 4) {
            int s0 = ssrc[p0 + j + 0];
            int s1 = ssrc[p0 + j + 1];
            int s2 = ssrc[p0 + j + 2];
            int s3 = ssrc[p0 + j + 3];
            float w0 = wrow[j + 0], w1 = wrow[j + 1], w2 = wrow[j + 2], w3 = wrow[j + 3];
            float2 f0 = __half22float2(((const __half2*)(xl + (size_t)s0 * HIDD))[lane]);
            float2 f1 = __half22float2(((const __half2*)(xl + (size_t)s1 * HIDD))[lane]);
            float2 f2 = __half22float2(((const __half2*)(xl + (size_t)s2 * HIDD))[lane]);
            float2 f3 = __half22float2(((const __half2*)(xl + (size_t)s3 * HIDD))[lane]);
            acc0 = fmaf(w0, f0.x, acc0); acc1 = fmaf(w0, f0.y, acc1);
            acc0 = fmaf(w1, f1.x, acc0); acc1 = fmaf(w1, f1.y, acc1);
            acc0 = fmaf(w2, f2.x, acc0); acc1 = fmaf(w2, f2.y, acc1);
            acc0 = fmaf(w3, f3.x, acc0); acc1 = fmaf(w3, f3.y, acc1);
        }
        for (; j < deg; ++j) {
            int s0 = ssrc[p0 + j];
            float w0 = wrow[j];
            float2 f0 = __half22float2(((const __half2*)(xl + (size_t)s0 * HIDD))[lane]);
            acc0 = fmaf(w0, f0.x, acc0); acc1 = fmaf(w0, f0.y, acc1);
        }
    } else {
        // slow path (deg > 64): 3-pass recompute, no LDS, no barrier inside
        float mx[H], dn[H];
#pragma unroll
        for (int h = 0; h < H; ++h) mx[h] = -INFINITY;
        for (int base = 0; base < deg; base += 64) {
            int j = base + lane;
            if (j < deg) {
                int s = ssrc[p0 + j];
                float ea = sfew[p0 + j];
#pragma unroll
                for (int h = 0; h < H; ++h) {
                    float x_ = a_src[s * H + h] + adn[h] + ea * Kc[h];
                    x_ = (x_ > 0.f) ? x_ : 0.2f * x_;
                    mx[h] = fmaxf(mx[h], x_);
                }
            }
        }
#pragma unroll
        for (int h = 0; h < H; ++h) {
#pragma unroll
            for (int m_ = 1; m_ < 64; m_ <<= 1) mx[h] = fmaxf(mx[h], __shfl_xor(mx[h], m_, 64));
            dn[h] = 0.f;
        }
        for (int base = 0; base < deg; base += 64) {
            int j = base + lane;
            if (j < deg) {
                int s = ssrc[p0 + j];
                float ea = sfew[p0 + j];
#pragma unroll
                for (int h = 0; h < H; ++h) {
                    float x_ = a_src[s * H + h] + adn[h] + ea * Kc[h];
                    x_ = (x_ > 0.f) ? x_ : 0.2f * x_;
                    dn[h] += __expf(x_ - mx[h]);
                }
            }
        }
#pragma unroll
        for (int h = 0; h < H; ++h) {
#pragma unroll
            for (int m_ = 1; m_ < 64; m_ <<= 1) dn[h] += __shfl_xor(dn[h], m_, 64);
            dn[h] = 1.0f / (dn[h] + 1e-16f);
        }
        for (int j = 0; j < deg; ++j) {
            int s = ssrc[p0 + j];
            float ea = sfew[p0 + j];
            float wsel;
            if constexpr (H == 4) {
                float4 as = *(const float4*)(a_src + s * 4);
                float x0 = as.x + adn[0] + ea * Kc[0]; x0 = (x0 > 0.f) ? x0 : 0.2f * x0;
                float x1 = as.y + adn[1] + ea * Kc[1]; x1 = (x1 > 0.f) ? x1 : 0.2f * x1;
                float x2 = as.z + adn[2] + ea * Kc[2]; x2 = (x2 > 0.f) ? x2 : 0.2f * x2;
                float x3 = as.w + adn[3] + ea * Kc[3]; x3 = (x3 > 0.f) ? x3 : 0.2f * x3;
                float w0 = __expf(x0 - mx[0]) * dn[0];
                float w1 = __expf(x1 - mx[1]) * dn[1];
                float w2 = __expf(x2 - mx[2]) * dn[2];
                float w3 = __expf(x3 - mx[3]) * dn[3];
                wsel = (lane < 16) ? w0 : ((lane < 32) ? w1 : ((lane < 48) ? w2 : w3));
            } else {
                float x0 = a_src[s] + adn[0] + ea * Kc[0]; x0 = (x0 > 0.f) ? x0 : 0.2f * x0;
                wsel = __expf(x0 - mx[0]) * dn[0];
            }
            float2 f = __half22float2(((const __half2*)(xl + (size_t)s * HIDD))[lane]);
            acc0 = fmaf(wsel, f.x, acc0);
            acc1 = fmaf(wsel, f.y, acc1);
        }
    }

    // epilogue: + gat_bias, BN(eval), ELU; cols c0=2*lane, c0+1
    {
        int c0 = 2 * lane;
        float2 bi = *(const float2*)(bias + c0);
        float2 g  = *(const float2*)(bng + c0);
        float2 bb = *(const float2*)(bnb + c0);
        float2 mm = *(const float2*)(bnm + c0);
        float2 vv = *(const float2*)(bnv + c0);
        float o0 = acc0 + bi.x;
        o0 = (o0 - mm.x) * rsqrtf(vv.x + BN_EPS) * g.x + bb.x;
        o0 = (o0 > 0.f) ? o0 : (__expf(o0) - 1.f);
        float o1 = acc1 + bi.y;
        o1 = (o1 - mm.y) * rsqrtf(vv.y + BN_EPS) * g.y + bb.y;
        o1 = (o1 > 0.f) ? o1 : (__expf(o1) - 1.f);
        *(float2*)(hout + (size_t)n * HIDD + c0) = make_float2(o0, o1);
    }
}

// ---------------------------------------------------------------------------
// Classifier tail
// ---------------------------------------------------------------------------
__global__ void k_scaleW1(const float* __restrict__ W1, const float* __restrict__ sym,
                          float* __restrict__ W1s)
{
    int i = blockIdx.x * 256 + threadIdx.x;
    if (i < 128 * 64) W1s[i] = W1[i] * sym[i >> 6];
}

__global__ __launch_bounds__(256) void k_clf2(const float* __restrict__ c1,
                                              const float* __restrict__ W2,
                                              const float* __restrict__ b2,
                                              float* __restrict__ c2)
{
    __shared__ float Wl[64][32];
    int t = threadIdx.x;
#pragma unroll
    for (int j = 0; j < 2; ++j) {
        int idx = t + j * 256;
        ((float4*)Wl)[idx] = ((const float4*)W2)[idx];
    }
    __syncthreads();
    int n = blockIdx.x * 256 + t;
    if (n >= NN) return;
    float acc[32];
#pragma unroll
    for (int j = 0; j < 32; ++j) acc[j] = b2[j];
    const float* row = c1 + (long)n * 64;
#pragma unroll
    for (int k0 = 0; k0 < 64; k0 += 4) {
        float4 hv = *(const float4*)(row + k0);
#pragma unroll
        for (int kk = 0; kk < 4; ++kk) {
            float h_ = (&hv.x)[kk];
#pragma unroll
            for (int j4 = 0; j4 < 8; ++j4) {
                float4 w4 = *(float4*)&Wl[k0 + kk][j4 * 4];
                acc[j4 * 4 + 0] = fmaf(h_, w4.x, acc[j4 * 4 + 0]);
                acc[j4 * 4 + 1] = fmaf(h_, w4.y, acc[j4 * 4 + 1]);
                acc[j4 * 4 + 2] = fmaf(h_, w4.z, acc[j4 * 4 + 2]);
                acc[j4 * 4 + 3] = fmaf(h_, w4.w, acc[j4 * 4 + 3]);
            }
        }
    }
    float* o = c2 + (long)n * 32;
#pragma unroll
    for (int j4 = 0; j4 < 8; ++j4) {
        float4 v = make_float4(fmaxf(acc[j4 * 4 + 0], 0.f), fmaxf(acc[j4 * 4 + 1], 0.f),
                               fmaxf(acc[j4 * 4 + 2], 0.f), fmaxf(acc[j4 * 4 + 3], 0.f));
        *(float4*)(o + j4 * 4) = v;
    }
}

__global__ __launch_bounds__(256) void k_clf3(const float* __restrict__ c2,
                                              const float* __restrict__ W3,
                                              const float* __restrict__ b3,
                                              float* __restrict__ out)
{
    int n = blockIdx.x * 256 + threadIdx.x;
    if (n >= NN) return;
    const float* row = c2 + (long)n * 32;
    float l0 = b3[0], l1 = b3[1];
#pragma unroll
    for (int k = 0; k < 32; ++k) {
        float cv = row[k];
        l0 = fmaf(cv, W3[k * 2 + 0], l0);
        l1 = fmaf(cv, W3[k * 2 + 1], l1);
    }
    *(float2*)(out + (long)n * 2) = make_float2(l0, l1);
}

// ---------------------------------------------------------------------------
extern "C" void kernel_launch(void* const* d_in, const int* in_sizes, int n_in,
                              void* d_out, int out_size, void* d_ws, size_t ws_size,
                              hipStream_t stream)
{
    const float* x          = (const float*)d_in[0];
    const int*   edge_index = (const int*)d_in[1];
    const float* edge_w     = (const float*)d_in[2];
    const float* Wproj      = (const float*)d_in[3];
    const float* bproj      = (const float*)d_in[4];
    const float* gat_W      = (const float*)d_in[5];
    const float* att_src    = (const float*)d_in[6];
    const float* att_dst    = (const float*)d_in[7];
    const float* att_edge   = (const float*)d_in[8];
    const float* lin_edge_W = (const float*)d_in[9];
    const float* gat_bias   = (const float*)d_in[10];
    const float* bn_g       = (const float*)d_in[11];
    const float* bn_b       = (const float*)d_in[12];
    const float* bn_m       = (const float*)d_in[13];
    const float* bn_v       = (const float*)d_in[14];
    const float* ew_W1      = (const float*)d_in[15];
    const float* ew_b1      = (const float*)d_in[16];
    const float* ew_W2      = (const float*)d_in[17];
    const float* ew_b2      = (const float*)d_in[18];
    const float* sym        = (const float*)d_in[19];
    const float* clf_W1     = (const float*)d_in[20];
    const float* clf_b1     = (const float*)d_in[21];
    const float* clf_bng    = (const float*)d_in[22];
    const float* clf_bnb    = (const float*)d_in[23];
    const float* clf_bnm    = (const float*)d_in[24];
    const float* clf_bnv    = (const float*)d_in[25];
    const float* clf_W2     = (const float*)d_in[26];
    const float* clf_b2     = (const float*)d_in[27];
    const float* clf_W3     = (const float*)d_in[28];
    const float* clf_b3     = (const float*)d_in[29];
    float* outp = (float*)d_out;

    // workspace layout (float slots); total ~112 MB (fits: prior runs passed)
    float* ws   = (float*)d_ws;
    float* hbuf = ws;                       // N*128 fp32
    float* xlf  = hbuf + 12800000;          // region of 12.8M float slots
    __half* xl  = (__half*)xlf;             // N*128 fp16 = first 6.4M float slots
    float* c1   = xlf;                      // N*64 fp32 (clf stage, after layers)
    int*   ssrc = (int*)(xlf + 6400000);    // ENL ints (aliases c2's region, disjoint in time)
    float* sfew = xlf + 7200000;            // ENL floats
    float* c2   = xlf + 6400000;            // N*32 fp32 (after last k_agg/ssrc use)
    float* asrc = xlf + 12800000;           // N*4
    float* adst = asrc + 400000;            // N*4
    float* fewp = adst + 400000;            // E
    float* scal = fewp + 640000;            // [0]=sumfew, [4..7]=Kc
    float* W1s  = scal + 16;                // 128*64
    int* rp   = (int*)(W1s + 8192);         // N+1 (rounded)
    int* cur  = rp + 100004;                // N
    int* eid  = cur + 100000;               // E+N
    int* part = eid + 740000;               // scan partials

    const int* esrc = edge_index;
    const int* edst = edge_index + EE;

    hipMemsetAsync(cur, 0, NN * sizeof(int), stream);

    // input projection: h = x @ Wproj + bproj
    k_gemm<64, 128, 0, 1><<<1563, 256, 0, stream>>>(
        x, Wproj, bproj, hbuf, NN,
        nullptr, nullptr, nullptr, nullptr, nullptr, nullptr, nullptr, nullptr);

    // CSR by dst (graph is layer-invariant) + CSR-order src permute
    k_hist<<<2891, 256, 0, stream>>>(edst, cur);
    k_scan1<<<391, 256, 0, stream>>>(cur, rp, part);
    k_scan2<<<1, 512, 0, stream>>>(part, 391);
    k_scan3<<<391, 256, 0, stream>>>(rp, cur, part);
    k_scatter<<<2891, 256, 0, stream>>>(edst, cur, eid);
    k_psrc<<<2891, 256, 0, stream>>>(eid, esrc, ssrc);

    for (int i = 0; i < 3; ++i) {
        int H = (i == 2) ? 1 : 4;
        k_prep<<<1, 128, 0, stream>>>(lin_edge_W + i * 128, att_edge + i * 128, scal, H);
        k_edgemlp<<<2500, 256, 0, stream>>>(edge_w, ew_W1 + i * 32, ew_b1 + i * 32,
                                            ew_W2 + i * 32, ew_b2 + i, fewp, scal);
        k_pfew<<<2891, 256, 0, stream>>>(eid, fewp, scal, sfew);
        if (H == 4) {
            k_gemm<128, 128, 1, 4><<<1563, 256, 0, stream>>>(
                hbuf, gat_W + i * 128 * 128, nullptr, xlf, NN,
                att_src + i * 128, att_dst + i * 128, asrc, adst,
                nullptr, nullptr, nullptr, nullptr);
            k_agg<4><<<25000, 256, 0, stream>>>(
                xl, asrc, adst, sfew, ssrc, scal, rp,
                gat_bias + i * 128, bn_g + i * 128, bn_b + i * 128,
                bn_m + i * 128, bn_v + i * 128, hbuf);
        } else {
            k_gemm<128, 128, 1, 1><<<1563, 256, 0, stream>>>(
                hbuf, gat_W + i * 128 * 128, nullptr, xlf, NN,
                att_src + i * 128, att_dst + i * 128, asrc, adst,
                nullptr, nullptr, nullptr, nullptr);
            k_agg<1><<<25000, 256, 0, stream>>>(
                xl, asrc, adst, sfew, ssrc, scal, rp,
                gat_bias + i * 128, bn_g + i * 128, bn_b + i * 128,
                bn_m + i * 128, bn_v + i * 128, hbuf);
        }
    }

    // classifier: fold sym into W1 rows, GEMM+relu+bn, then small dense layers
    k_scaleW1<<<32, 256, 0, stream>>>(clf_W1, sym, W1s);
    k_gemm<128, 64, 2, 1><<<1563, 256, 0, stream>>>(
        hbuf, W1s, clf_b1, c1, NN,
        nullptr, nullptr, nullptr, nullptr, clf_bng, clf_bnb, clf_bnm, clf_bnv);
    k_clf2<<<391, 256, 0, stream>>>(c1, clf_W2, clf_b2, c2);
    k_clf3<<<391, 256, 0, stream>>>(c2, clf_W3, clf_b3, outp);
}

// Round 11
// 737.561 us; speedup vs baseline: 1.3159x; 1.0632x over previous
//
#include <hip/hip_runtime.h>
#include <hip/hip_fp16.h>
#include <math.h>

#define NN 100000
#define EE 640000
#define ENL (EE + NN)
#define HIDD 128

constexpr float BN_EPS = 1e-5f;

typedef _Float16 f16x8 __attribute__((ext_vector_type(8)));
typedef float f32x4 __attribute__((ext_vector_type(4)));

// ---------------------------------------------------------------------------
// Tiled fp32 GEMM (kept for proj + classifier stage 1):
// EPI 0: + bias, fp32 out                (projection)
// EPI 2: + bias, relu, then BN, fp32 out (classifier stage 1)
// Block tile: 64 rows x NC cols, k-tile 32. 256 threads.
// ---------------------------------------------------------------------------
template<int KDIM, int NC, int EPI>
__global__ __launch_bounds__(256) void k_gemm(
    const float* __restrict__ A, const float* __restrict__ W,
    const float* __restrict__ bias, float* __restrict__ out, int nrows,
    const float* __restrict__ bng, const float* __restrict__ bnb,
    const float* __restrict__ bnm, const float* __restrict__ bnv)
{
    constexpr int TXN = NC / 4;       // thread groups along cols
    constexpr int TYN = 256 / TXN;    // row groups
    constexpr int RPT = 64 / TYN;     // rows per thread
    __shared__ float Al[64][36];      // pad 36: fp32x4-aligned, 2-way bank (free)
    __shared__ float Wl[32][NC];
    const int t = threadIdx.x;
    const int tx = t % TXN, ty = t / TXN;
    const long rowBase = (long)blockIdx.x * 64;
    float acc[RPT][4];
#pragma unroll
    for (int r = 0; r < RPT; ++r) { acc[r][0]=0.f; acc[r][1]=0.f; acc[r][2]=0.f; acc[r][3]=0.f; }

    for (int kk = 0; kk < KDIM; kk += 32) {
#pragma unroll
        for (int j = 0; j < 2; ++j) {
            int idx = t + j * 256;
            int r = idx >> 3;
            int k4 = (idx & 7) << 2;
            long gr = rowBase + r;
            float4 v = make_float4(0.f, 0.f, 0.f, 0.f);
            if (gr < nrows) v = *(const float4*)(A + gr * KDIM + kk + k4);
            *(float4*)&Al[r][k4] = v;
        }
        constexpr int WLOAD = (32 * NC / 4) / 256;
#pragma unroll
        for (int j = 0; j < WLOAD; ++j) {
            int idx = t + j * 256;
            int k = idx / TXN;
            int c4 = (idx % TXN) << 2;
            *(float4*)&Wl[k][c4] = *(const float4*)(W + (long)(kk + k) * NC + c4);
        }
        __syncthreads();
#pragma unroll
        for (int k = 0; k < 32; ++k) {
            float4 wv = *(float4*)&Wl[k][tx * 4];
#pragma unroll
            for (int r = 0; r < RPT; ++r) {
                float av = Al[ty * RPT + r][k];
                acc[r][0] = fmaf(av, wv.x, acc[r][0]);
                acc[r][1] = fmaf(av, wv.y, acc[r][1]);
                acc[r][2] = fmaf(av, wv.z, acc[r][2]);
                acc[r][3] = fmaf(av, wv.w, acc[r][3]);
            }
        }
        __syncthreads();
    }

    const int col0 = tx * 4;
    if constexpr (EPI == 0) {
        float4 b4 = *(const float4*)(bias + col0);
#pragma unroll
        for (int r = 0; r < RPT; ++r) {
            long row = rowBase + ty * RPT + r;
            if (row < nrows) {
                float4 o = make_float4(acc[r][0] + b4.x, acc[r][1] + b4.y,
                                       acc[r][2] + b4.z, acc[r][3] + b4.w);
                *(float4*)(out + row * NC + col0) = o;
            }
        }
    } else { // EPI == 2: bias -> relu -> bn
        float4 b4 = *(const float4*)(bias + col0);
        float4 g4 = *(const float4*)(bng + col0);
        float4 be4 = *(const float4*)(bnb + col0);
        float4 m4 = *(const float4*)(bnm + col0);
        float4 v4 = *(const float4*)(bnv + col0);
        float s0 = rsqrtf(v4.x + BN_EPS) * g4.x;
        float s1 = rsqrtf(v4.y + BN_EPS) * g4.y;
        float s2 = rsqrtf(v4.z + BN_EPS) * g4.z;
        float s3 = rsqrtf(v4.w + BN_EPS) * g4.w;
#pragma unroll
        for (int r = 0; r < RPT; ++r) {
            long row = rowBase + ty * RPT + r;
            if (row < nrows) {
                float o0 = fmaxf(acc[r][0] + b4.x, 0.f);
                float o1 = fmaxf(acc[r][1] + b4.y, 0.f);
                float o2 = fmaxf(acc[r][2] + b4.z, 0.f);
                float o3 = fmaxf(acc[r][3] + b4.w, 0.f);
                float4 o = make_float4((o0 - m4.x) * s0 + be4.x,
                                       (o1 - m4.y) * s1 + be4.y,
                                       (o2 - m4.z) * s2 + be4.z,
                                       (o3 - m4.w) * s3 + be4.w);
                *(float4*)(out + row * NC + col0) = o;
            }
        }
    }
}

// ---------------------------------------------------------------------------
// W transpose+cast for MFMA: Wt[n][k] = (fp16) W[k][n], 128x128 per layer.
// ---------------------------------------------------------------------------
__global__ void k_prepW(const float* __restrict__ Wk, __half* __restrict__ Wt)
{
    int idx = blockIdx.x * 256 + threadIdx.x;   // 16384
    int k = idx >> 7, n = idx & 127;
    Wt[n * 128 + k] = (__half)Wk[idx];          // coalesced read, scattered 2B write (tiny)
}

// ---------------------------------------------------------------------------
// MFMA GEMM for GAT layers: xl[nrows,128] = fp16( A[nrows,128] @ W )
// A fp32 (cast to fp16 in staging), Wt = W^T fp16 [n][k].
// Block 256 thr = 4 waves; 64 rows/block; wave w owns rows [16w,16w+16).
// mfma_f32_16x16x32_f16: A-frag lane l = A[l&15][8*(l>>4)+j]; B-frag
// lane l = B[8*(l>>4)+j][l&15] = Wt[l&15][8*(l>>4)+j]; C/D col=l&15,
// row=4*(l>>4)+reg. LDS pad 136 fp16 (272B=68 dw, 4-bank shift/row -> 2-way, free).
// ---------------------------------------------------------------------------
__global__ __launch_bounds__(256) void k_mgemm(
    const float* __restrict__ A, const __half* __restrict__ Wt,
    __half* __restrict__ xlh, int nrows)
{
    __shared__ _Float16 Ah[64][136];     // 17.0 KB (reused as output staging)
    __shared__ _Float16 Wl[128][136];    // 34.0 KB
    const int t = threadIdx.x;
    const int lane = t & 63, w = t >> 6;
    const long rowBase = (long)blockIdx.x * 64;

    // stage A: 64x128 fp32 -> fp16 (2048 float4 chunks)
#pragma unroll
    for (int j = 0; j < 8; ++j) {
        int flat = t + j * 256;
        int r = flat >> 5;               // 32 chunks per row
        int c4 = (flat & 31) << 2;
        float4 v = make_float4(0.f, 0.f, 0.f, 0.f);
        long gr = rowBase + r;
        if (gr < nrows) v = *(const float4*)(A + gr * 128 + c4);
        _Float16* dst = &Ah[r][c4];
        dst[0] = (_Float16)v.x; dst[1] = (_Float16)v.y;
        dst[2] = (_Float16)v.z; dst[3] = (_Float16)v.w;
    }
    // stage Wt: 128x128 fp16 (2048 16B chunks)
#pragma unroll
    for (int j = 0; j < 8; ++j) {
        int flat = t + j * 256;
        int r = flat >> 4;               // 16 chunks per row
        int ch = (flat & 15) << 3;
        *(uint4*)&Wl[r][ch] = *(const uint4*)(Wt + r * 128 + ch);
    }
    __syncthreads();

    const int row16 = lane & 15, kb = lane >> 4;
    f32x4 acc[8];
#pragma unroll
    for (int cb = 0; cb < 8; ++cb) acc[cb] = (f32x4){0.f, 0.f, 0.f, 0.f};
#pragma unroll
    for (int ks = 0; ks < 4; ++ks) {
        f16x8 a = *(const f16x8*)&Ah[w * 16 + row16][ks * 32 + kb * 8];
#pragma unroll
        for (int cb = 0; cb < 8; ++cb) {
            f16x8 b = *(const f16x8*)&Wl[cb * 16 + row16][ks * 32 + kb * 8];
            acc[cb] = __builtin_amdgcn_mfma_f32_16x16x32_f16(a, b, acc[cb], 0, 0, 0);
        }
    }

    // epilogue: acc -> Oh (reuse Ah; each wave touches only its own 16 rows,
    // and its MFMA reads of those rows are data-complete before these writes)
    _Float16 (*Oh)[136] = Ah;
#pragma unroll
    for (int cb = 0; cb < 8; ++cb) {
#pragma unroll
        for (int r = 0; r < 4; ++r) {
            Oh[w * 16 + kb * 4 + r][cb * 16 + row16] = (_Float16)acc[cb][r];
        }
    }
    __syncthreads();                     // cross-wave: store loop reads all rows
    // coalesced store: 64x128 fp16 = 1024 16B chunks
#pragma unroll
    for (int j = 0; j < 4; ++j) {
        int flat = t + j * 256;
        int r = flat >> 4;
        int ch = (flat & 15) << 3;
        long gr = rowBase + r;
        if (gr < nrows) *(uint4*)(xlh + gr * 128 + ch) = *(const uint4*)&Oh[r][ch];
    }
}

// ---------------------------------------------------------------------------
// a_src/a_dst from fp16 xl: one thread per (row, head). asrc[row*H+h].
// ---------------------------------------------------------------------------
template<int H>
__global__ __launch_bounds__(256) void k_att(
    const __half* __restrict__ xlh, const float* __restrict__ att_s,
    const float* __restrict__ att_d, float* __restrict__ asrc,
    float* __restrict__ adst)
{
    int gid = blockIdx.x * 256 + threadIdx.x;
    if (gid >= NN * H) return;
    int row = gid / H, h = gid % H;
    constexpr int C = 128 / H;
    const __half* xr = xlh + (size_t)row * 128 + h * C;
    const float* as = att_s + h * C;
    const float* ad = att_d + h * C;
    float ps = 0.f, pd = 0.f;
#pragma unroll
    for (int c = 0; c < C; c += 2) {
        float2 f = __half22float2(*(const __half2*)(xr + c));
        ps = fmaf(f.x, as[c], ps); ps = fmaf(f.y, as[c + 1], ps);
        pd = fmaf(f.x, ad[c], pd); pd = fmaf(f.y, ad[c + 1], pd);
    }
    asrc[gid] = ps;
    adst[gid] = pd;
}

// ---------------------------------------------------------------------------
// Per-layer tiny prep: Kc[h] = sum_c lin_edge_W[h*C+c]*att_edge[h*C+c]; zero sumfew
// ---------------------------------------------------------------------------
__global__ void k_prep(const float* __restrict__ lew, const float* __restrict__ ae,
                       float* __restrict__ scal, int H)
{
    __shared__ float p[128];
    int t = threadIdx.x;
    p[t] = lew[t] * ae[t];
    __syncthreads();
    if (t == 0) scal[0] = 0.f;
    if (t < H) {
        int Cc = 128 / H;
        float s = 0.f;
        for (int c = 0; c < Cc; ++c) s += p[t * Cc + c];
        scal[4 + t] = s;
    }
}

// ---------------------------------------------------------------------------
// Edge MLP: few[e] = ew * sigmoid( relu(ew*W1+b1) @ W2 + b2 ); also sum(few)
// ---------------------------------------------------------------------------
__global__ __launch_bounds__(256) void k_edgemlp(
    const float* __restrict__ ew, const float* __restrict__ W1,
    const float* __restrict__ b1, const float* __restrict__ W2,
    const float* __restrict__ b2, float* __restrict__ few,
    float* __restrict__ sumfew)
{
    __shared__ float red[4];
    int e = blockIdx.x * 256 + threadIdx.x;
    float f = 0.f;
    if (e < EE) {
        float w = ew[e];
        float acc = b2[0];
#pragma unroll
        for (int j = 0; j < 32; ++j) {
            float t_ = fmaf(w, W1[j], b1[j]);
            t_ = fmaxf(t_, 0.f);
            acc = fmaf(t_, W2[j], acc);
        }
        f = w / (1.f + __expf(-acc));
        few[e] = f;
    }
    float s = f;
#pragma unroll
    for (int m_ = 1; m_ < 64; m_ <<= 1) s += __shfl_xor(s, m_, 64);
    int lane = threadIdx.x & 63, wid = threadIdx.x >> 6;
    if (lane == 0) red[wid] = s;
    __syncthreads();
    if (threadIdx.x == 0) atomicAdd(sumfew, red[0] + red[1] + red[2] + red[3]);
}

// ---------------------------------------------------------------------------
// CSR build: hist -> 2-level exclusive scan -> scatter (bucket by dst)
// ---------------------------------------------------------------------------
__global__ __launch_bounds__(256) void k_hist(const int* __restrict__ edst, int* __restrict__ cnt)
{
    int e = blockIdx.x * 256 + threadIdx.x;
    if (e < ENL) {
        int d = (e < EE) ? edst[e] : (e - EE);
        atomicAdd(&cnt[d], 1);
    }
}

__global__ __launch_bounds__(256) void k_scan1(const int* __restrict__ cnt,
                                               int* __restrict__ tmp, int* __restrict__ part)
{
    __shared__ int s1[256];
    int t = threadIdx.x;
    int i = blockIdx.x * 256 + t;
    int x = (i < NN) ? cnt[i] : 0;
    s1[t] = x;
    __syncthreads();
#pragma unroll
    for (int off = 1; off < 256; off <<= 1) {
        int v_ = (t >= off) ? s1[t - off] : 0;
        __syncthreads();
        s1[t] += v_;
        __syncthreads();
    }
    if (i < NN) tmp[i] = s1[t] - x;
    if (t == 255) part[blockIdx.x] = s1[255];
}

__global__ void k_scan2(int* __restrict__ part, int nb)
{
    __shared__ int s1[512];
    int t = threadIdx.x;
    int x = (t < nb) ? part[t] : 0;
    s1[t] = x;
    __syncthreads();
#pragma unroll
    for (int off = 1; off < 512; off <<= 1) {
        int v_ = (t >= off) ? s1[t - off] : 0;
        __syncthreads();
        s1[t] += v_;
        __syncthreads();
    }
    if (t < nb) part[t] = s1[t] - x;
}

__global__ __launch_bounds__(256) void k_scan3(int* __restrict__ rp, int* __restrict__ cur,
                                               const int* __restrict__ part)
{
    int i = blockIdx.x * 256 + threadIdx.x;
    if (i < NN) {
        int v_ = rp[i] + part[blockIdx.x];
        rp[i] = v_;
        cur[i] = v_;
    } else if (i == NN) {
        rp[NN] = ENL;
    }
}

__global__ __launch_bounds__(256) void k_scatter(const int* __restrict__ edst,
                                                 int* __restrict__ cur, int* __restrict__ eid)
{
    int e = blockIdx.x * 256 + threadIdx.x;
    if (e < ENL) {
        int d = (e < EE) ? edst[e] : (e - EE);
        int pos = atomicAdd(&cur[d], 1);
        eid[pos] = e;
    }
}

// ---------------------------------------------------------------------------
// CSR-order permutes: kill the eid indirection in the hot loops.
// ---------------------------------------------------------------------------
__global__ __launch_bounds__(256) void k_psrc(const int* __restrict__ eid,
                                              const int* __restrict__ esrc,
                                              int* __restrict__ ssrc)
{
    int p = blockIdx.x * 256 + threadIdx.x;
    if (p < ENL) {
        int e = eid[p];
        ssrc[p] = (e < EE) ? esrc[e] : (e - EE);
    }
}

__global__ __launch_bounds__(256) void k_pfew(const int* __restrict__ eid,
                                              const float* __restrict__ few,
                                              const float* __restrict__ scal,
                                              float* __restrict__ sfew)
{
    int p = blockIdx.x * 256 + threadIdx.x;
    if (p < ENL) {
        int e = eid[p];
        sfew[p] = (e < EE) ? few[e] : scal[0] * (1.0f / EE);
    }
}

// ---------------------------------------------------------------------------
// Per-node GAT softmax + aggregation (unchanged from verified R10 kernel).
// ---------------------------------------------------------------------------
template<int H>
__global__ __launch_bounds__(256) void k_agg(
    const __half* __restrict__ xl, const float* __restrict__ a_src,
    const float* __restrict__ a_dst, const float* __restrict__ sfew,
    const int* __restrict__ ssrc, const float* __restrict__ scal,
    const int* __restrict__ rp,
    const float* __restrict__ bias, const float* __restrict__ bng,
    const float* __restrict__ bnb, const float* __restrict__ bnm,
    const float* __restrict__ bnv, float* __restrict__ hout)
{
    __shared__ float lw[4][H][66];
    const int lane = threadIdx.x & 63;
    const int wid  = threadIdx.x >> 6;
    const int n = (blockIdx.x << 2) + wid;   // grid = 25000*4 == NN exactly
    float Kc[H], adn[H];
#pragma unroll
    for (int h = 0; h < H; ++h) { Kc[h] = scal[4 + h]; adn[h] = a_dst[n * H + h]; }
    const int p0 = rp[n];
    const int deg = rp[n + 1] - p0;
    const bool fast = (deg <= 64);

    float acc0 = 0.f, acc1 = 0.f;

    if (fast) {
        const bool act = lane < deg;
        float al[H];
        if (act) {
            int s = ssrc[p0 + lane];
            float ea = sfew[p0 + lane];
            if constexpr (H == 4) {
                float4 as = *(const float4*)(a_src + s * 4);
                float x0 = as.x + adn[0] + ea * Kc[0];
                float x1 = as.y + adn[1] + ea * Kc[1];
                float x2 = as.z + adn[2] + ea * Kc[2];
                float x3 = as.w + adn[3] + ea * Kc[3];
                al[0] = (x0 > 0.f) ? x0 : 0.2f * x0;
                al[1] = (x1 > 0.f) ? x1 : 0.2f * x1;
                al[2] = (x2 > 0.f) ? x2 : 0.2f * x2;
                al[3] = (x3 > 0.f) ? x3 : 0.2f * x3;
            } else {
                float x0 = a_src[s] + adn[0] + ea * Kc[0];
                al[0] = (x0 > 0.f) ? x0 : 0.2f * x0;
            }
        } else {
#pragma unroll
            for (int h = 0; h < H; ++h) al[h] = -INFINITY;
        }
        float mx[H], ex[H], dn[H];
#pragma unroll
        for (int h = 0; h < H; ++h) {
            mx[h] = al[h];
#pragma unroll
            for (int m_ = 1; m_ < 64; m_ <<= 1) mx[h] = fmaxf(mx[h], __shfl_xor(mx[h], m_, 64));
        }
#pragma unroll
        for (int h = 0; h < H; ++h) {
            ex[h] = act ? __expf(al[h] - mx[h]) : 0.f;
            dn[h] = ex[h];
#pragma unroll
            for (int m_ = 1; m_ < 64; m_ <<= 1) dn[h] += __shfl_xor(dn[h], m_, 64);
            lw[wid][h][lane] = ex[h] * (1.0f / (dn[h] + 1e-16f));
        }
    }
    __syncthreads();   // single barrier, reached by every wave exactly once

    if (fast) {
        const int myh = (H == 4) ? (lane >> 4) : 0;
        const float* wrow = &lw[wid][myh][0];
        int j = 0;
        for (; j + 4 <= deg; j += 4) {
            int s0 = ssrc[p0 + j + 0];
            int s1 = ssrc[p0 + j + 1];
            int s2 = ssrc[p0 + j + 2];
            int s3 = ssrc[p0 + j + 3];
            float w0 = wrow[j + 0], w1 = wrow[j + 1], w2 = wrow[j + 2], w3 = wrow[j + 3];
            float2 f0 = __half22float2(((const __half2*)(xl + (size_t)s0 * HIDD))[lane]);
            float2 f1 = __half22float2(((const __half2*)(xl + (size_t)s1 * HIDD))[lane]);
            float2 f2 = __half22float2(((const __half2*)(xl + (size_t)s2 * HIDD))[lane]);
            float2 f3 = __half22float2(((const __half2*)(xl + (size_t)s3 * HIDD))[lane]);
            acc0 = fmaf(w0, f0.x, acc0); acc1 = fmaf(w0, f0.y, acc1);
            acc0 = fmaf(w1, f1.x, acc0); acc1 = fmaf(w1, f1.y, acc1);
            acc0 = fmaf(w2, f2.x, acc0); acc1 = fmaf(w2, f2.y, acc1);
            acc0 = fmaf(w3, f3.x, acc0); acc1 = fmaf(w3, f3.y, acc1);
        }
        for (; j < deg; ++j) {
            int s0 = ssrc[p0 + j];
            float w0 = wrow[j];
            float2 f0 = __half22float2(((const __half2*)(xl + (size_t)s0 * HIDD))[lane]);
            acc0 = fmaf(w0, f0.x, acc0); acc1 = fmaf(w0, f0.y, acc1);
        }
    } else {
        // slow path (deg > 64): 3-pass recompute, no LDS, no barrier inside
        float mx[H], dn[H];
#pragma unroll
        for (int h = 0; h < H; ++h) mx[h] = -INFINITY;
        for (int base = 0; base < deg; base += 64) {
            int j = base + lane;
            if (j < deg) {
                int s = ssrc[p0 + j];
                float ea = sfew[p0 + j];
#pragma unroll
                for (int h = 0; h < H; ++h) {
                    float x_ = a_src[s * H + h] + adn[h] + ea * Kc[h];
                    x_ = (x_ > 0.f) ? x_ : 0.2f * x_;
                    mx[h] = fmaxf(mx[h], x_);
                }
            }
        }
#pragma unroll
        for (int h = 0; h < H; ++h) {
#pragma unroll
            for (int m_ = 1; m_ < 64; m_ <<= 1) mx[h] = fmaxf(mx[h], __shfl_xor(mx[h], m_, 64));
            dn[h] = 0.f;
        }
        for (int base = 0; base < deg; base += 64) {
            int j = base + lane;
            if (j < deg) {
                int s = ssrc[p0 + j];
                float ea = sfew[p0 + j];
#pragma unroll
                for (int h = 0; h < H; ++h) {
                    float x_ = a_src[s * H + h] + adn[h] + ea * Kc[h];
                    x_ = (x_ > 0.f) ? x_ : 0.2f * x_;
                    dn[h] += __expf(x_ - mx[h]);
                }
            }
        }
#pragma unroll
        for (int h = 0; h < H; ++h) {
#pragma unroll
            for (int m_ = 1; m_ < 64; m_ <<= 1) dn[h] += __shfl_xor(dn[h], m_, 64);
            dn[h] = 1.0f / (dn[h] + 1e-16f);
        }
        for (int j = 0; j < deg; ++j) {
            int s = ssrc[p0 + j];
            float ea = sfew[p0 + j];
            float wsel;
            if constexpr (H == 4) {
                float4 as = *(const float4*)(a_src + s * 4);
                float x0 = as.x + adn[0] + ea * Kc[0]; x0 = (x0 > 0.f) ? x0 : 0.2f * x0;
                float x1 = as.y + adn[1] + ea * Kc[1]; x1 = (x1 > 0.f) ? x1 : 0.2f * x1;
                float x2 = as.z + adn[2] + ea * Kc[2]; x2 = (x2 > 0.f) ? x2 : 0.2f * x2;
                float x3 = as.w + adn[3] + ea * Kc[3]; x3 = (x3 > 0.f) ? x3 : 0.2f * x3;
                float w0 = __expf(x0 - mx[0]) * dn[0];
                float w1 = __expf(x1 - mx[1]) * dn[1];
                float w2 = __expf(x2 - mx[2]) * dn[2];
                float w3 = __expf(x3 - mx[3]) * dn[3];
                wsel = (lane < 16) ? w0 : ((lane < 32) ? w1 : ((lane < 48) ? w2 : w3));
            } else {
                float x0 = a_src[s] + adn[0] + ea * Kc[0]; x0 = (x0 > 0.f) ? x0 : 0.2f * x0;
                wsel = __expf(x0 - mx[0]) * dn[0];
            }
            float2 f = __half22float2(((const __half2*)(xl + (size_t)s * HIDD))[lane]);
            acc0 = fmaf(wsel, f.x, acc0);
            acc1 = fmaf(wsel, f.y, acc1);
        }
    }

    // epilogue: + gat_bias, BN(eval), ELU; cols c0=2*lane, c0+1
    {
        int c0 = 2 * lane;
        float2 bi = *(const float2*)(bias + c0);
        float2 g  = *(const float2*)(bng + c0);
        float2 bb = *(const float2*)(bnb + c0);
        float2 mm = *(const float2*)(bnm + c0);
        float2 vv = *(const float2*)(bnv + c0);
        float o0 = acc0 + bi.x;
        o0 = (o0 - mm.x) * rsqrtf(vv.x + BN_EPS) * g.x + bb.x;
        o0 = (o0 > 0.f) ? o0 : (__expf(o0) - 1.f);
        float o1 = acc1 + bi.y;
        o1 = (o1 - mm.y) * rsqrtf(vv.y + BN_EPS) * g.y + bb.y;
        o1 = (o1 > 0.f) ? o1 : (__expf(o1) - 1.f);
        *(float2*)(hout + (size_t)n * HIDD + c0) = make_float2(o0, o1);
    }
}

// ---------------------------------------------------------------------------
// Classifier tail
// ---------------------------------------------------------------------------
__global__ void k_scaleW1(const float* __restrict__ W1, const float* __restrict__ sym,
                          float* __restrict__ W1s)
{
    int i = blockIdx.x * 256 + threadIdx.x;
    if (i < 128 * 64) W1s[i] = W1[i] * sym[i >> 6];
}

__global__ __launch_bounds__(256) void k_clf2(const float* __restrict__ c1,
                                              const float* __restrict__ W2,
                                              const float* __restrict__ b2,
                                              float* __restrict__ c2)
{
    __shared__ float Wl[64][32];
    int t = threadIdx.x;
#pragma unroll
    for (int j = 0; j < 2; ++j) {
        int idx = t + j * 256;
        ((float4*)Wl)[idx] = ((const float4*)W2)[idx];
    }
    __syncthreads();
    int n = blockIdx.x * 256 + t;
    if (n >= NN) return;
    float acc[32];
#pragma unroll
    for (int j = 0; j < 32; ++j) acc[j] = b2[j];
    const float* row = c1 + (long)n * 64;
#pragma unroll
    for (int k0 = 0; k0 < 64; k0 += 4) {
        float4 hv = *(const float4*)(row + k0);
#pragma unroll
        for (int kk = 0; kk < 4; ++kk) {
            float h_ = (&hv.x)[kk];
#pragma unroll
            for (int j4 = 0; j4 < 8; ++j4) {
                float4 w4 = *(float4*)&Wl[k0 + kk][j4 * 4];
                acc[j4 * 4 + 0] = fmaf(h_, w4.x, acc[j4 * 4 + 0]);
                acc[j4 * 4 + 1] = fmaf(h_, w4.y, acc[j4 * 4 + 1]);
                acc[j4 * 4 + 2] = fmaf(h_, w4.z, acc[j4 * 4 + 2]);
                acc[j4 * 4 + 3] = fmaf(h_, w4.w, acc[j4 * 4 + 3]);
            }
        }
    }
    float* o = c2 + (long)n * 32;
#pragma unroll
    for (int j4 = 0; j4 < 8; ++j4) {
        float4 v = make_float4(fmaxf(acc[j4 * 4 + 0], 0.f), fmaxf(acc[j4 * 4 + 1], 0.f),
                               fmaxf(acc[j4 * 4 + 2], 0.f), fmaxf(acc[j4 * 4 + 3], 0.f));
        *(float4*)(o + j4 * 4) = v;
    }
}

__global__ __launch_bounds__(256) void k_clf3(const float* __restrict__ c2,
                                              const float* __restrict__ W3,
                                              const float* __restrict__ b3,
                                              float* __restrict__ out)
{
    int n = blockIdx.x * 256 + threadIdx.x;
    if (n >= NN) return;
    const float* row = c2 + (long)n * 32;
    float l0 = b3[0], l1 = b3[1];
#pragma unroll
    for (int k = 0; k < 32; ++k) {
        float cv = row[k];
        l0 = fmaf(cv, W3[k * 2 + 0], l0);
        l1 = fmaf(cv, W3[k * 2 + 1], l1);
    }
    *(float2*)(out + (long)n * 2) = make_float2(l0, l1);
}

// ---------------------------------------------------------------------------
extern "C" void kernel_launch(void* const* d_in, const int* in_sizes, int n_in,
                              void* d_out, int out_size, void* d_ws, size_t ws_size,
                              hipStream_t stream)
{
    const float* x          = (const float*)d_in[0];
    const int*   edge_index = (const int*)d_in[1];
    const float* edge_w     = (const float*)d_in[2];
    const float* Wproj      = (const float*)d_in[3];
    const float* bproj      = (const float*)d_in[4];
    const float* gat_W      = (const float*)d_in[5];
    const float* att_src    = (const float*)d_in[6];
    const float* att_dst    = (const float*)d_in[7];
    const float* att_edge   = (const float*)d_in[8];
    const float* lin_edge_W = (const float*)d_in[9];
    const float* gat_bias   = (const float*)d_in[10];
    const float* bn_g       = (const float*)d_in[11];
    const float* bn_b       = (const float*)d_in[12];
    const float* bn_m       = (const float*)d_in[13];
    const float* bn_v       = (const float*)d_in[14];
    const float* ew_W1      = (const float*)d_in[15];
    const float* ew_b1      = (const float*)d_in[16];
    const float* ew_W2      = (const float*)d_in[17];
    const float* ew_b2      = (const float*)d_in[18];
    const float* sym        = (const float*)d_in[19];
    const float* clf_W1     = (const float*)d_in[20];
    const float* clf_b1     = (const float*)d_in[21];
    const float* clf_bng    = (const float*)d_in[22];
    const float* clf_bnb    = (const float*)d_in[23];
    const float* clf_bnm    = (const float*)d_in[24];
    const float* clf_bnv    = (const float*)d_in[25];
    const float* clf_W2     = (const float*)d_in[26];
    const float* clf_b2     = (const float*)d_in[27];
    const float* clf_W3     = (const float*)d_in[28];
    const float* clf_b3     = (const float*)d_in[29];
    float* outp = (float*)d_out;

    // workspace layout (float slots); ~112 MB + 32KB Wt_h (prior runs passed)
    float* ws   = (float*)d_ws;
    float* hbuf = ws;                       // N*128 fp32
    float* xlf  = hbuf + 12800000;          // region of 12.8M float slots
    __half* xl  = (__half*)xlf;             // N*128 fp16 = first 6.4M float slots
    float* c1   = xlf;                      // N*64 fp32 (clf stage, after layers)
    int*   ssrc = (int*)(xlf + 6400000);    // ENL ints (aliases c2, disjoint in time)
    float* sfew = xlf + 7200000;            // ENL floats
    float* c2   = xlf + 6400000;            // N*32 fp32 (after last k_agg/ssrc use)
    float* asrc = xlf + 12800000;           // N*4
    float* adst = asrc + 400000;            // N*4
    float* fewp = adst + 400000;            // E
    float* scal = fewp + 640000;            // [0]=sumfew, [4..7]=Kc
    float* W1s  = scal + 16;                // 128*64
    __half* Wt_h = (__half*)(W1s + 8192);   // 128*128 fp16 (8192 float slots)
    int* rp   = (int*)(W1s + 8192 + 8192);  // N+1 (rounded)
    int* cur  = rp + 100004;                // N
    int* eid  = cur + 100000;               // E+N
    int* part = eid + 740000;               // scan partials

    const int* esrc = edge_index;
    const int* edst = edge_index + EE;

    hipMemsetAsync(cur, 0, NN * sizeof(int), stream);

    // input projection: h = x @ Wproj + bproj (fp32)
    k_gemm<64, 128, 0><<<1563, 256, 0, stream>>>(
        x, Wproj, bproj, hbuf, NN, nullptr, nullptr, nullptr, nullptr);

    // CSR by dst (graph is layer-invariant) + CSR-order src permute
    k_hist<<<2891, 256, 0, stream>>>(edst, cur);
    k_scan1<<<391, 256, 0, stream>>>(cur, rp, part);
    k_scan2<<<1, 512, 0, stream>>>(part, 391);
    k_scan3<<<391, 256, 0, stream>>>(rp, cur, part);
    k_scatter<<<2891, 256, 0, stream>>>(edst, cur, eid);
    k_psrc<<<2891, 256, 0, stream>>>(eid, esrc, ssrc);

    for (int i = 0; i < 3; ++i) {
        int H = (i == 2) ? 1 : 4;
        k_prep<<<1, 128, 0, stream>>>(lin_edge_W + i * 128, att_edge + i * 128, scal, H);
        k_edgemlp<<<2500, 256, 0, stream>>>(edge_w, ew_W1 + i * 32, ew_b1 + i * 32,
                                            ew_W2 + i * 32, ew_b2 + i, fewp, scal);
        k_pfew<<<2891, 256, 0, stream>>>(eid, fewp, scal, sfew);
        // MFMA GEMM: Wt = W^T fp16, then xl = fp16(h @ W), then a_src/a_dst
        k_prepW<<<64, 256, 0, stream>>>(gat_W + i * 128 * 128, Wt_h);
        k_mgemm<<<1563, 256, 0, stream>>>(hbuf, Wt_h, xl, NN);
        if (H == 4) {
            k_att<4><<<1563, 256, 0, stream>>>(xl, att_src + i * 128, att_dst + i * 128,
                                               asrc, adst);
            k_agg<4><<<25000, 256, 0, stream>>>(
                xl, asrc, adst, sfew, ssrc, scal, rp,
                gat_bias + i * 128, bn_g + i * 128, bn_b + i * 128,
                bn_m + i * 128, bn_v + i * 128, hbuf);
        } else {
            k_att<1><<<391, 256, 0, stream>>>(xl, att_src + i * 128, att_dst + i * 128,
                                              asrc, adst);
            k_agg<1><<<25000, 256, 0, stream>>>(
                xl, asrc, adst, sfew, ssrc, scal, rp,
                gat_bias + i * 128, bn_g + i * 128, bn_b + i * 128,
                bn_m + i * 128, bn_v + i * 128, hbuf);
        }
    }

    // classifier: fold sym into W1 rows, GEMM+relu+bn, then small dense layers
    k_scaleW1<<<32, 256, 0, stream>>>(clf_W1, sym, W1s);
    k_gemm<128, 64, 2><<<1563, 256, 0, stream>>>(
        hbuf, W1s, clf_b1, c1, NN, clf_bng, clf_bnb, clf_bnm, clf_bnv);
    k_clf2<<<391, 256, 0, stream>>>(c1, clf_W2, clf_b2, c2);
    k_clf3<<<391, 256, 0, stream>>>(c2, clf_W3, clf_b3, outp);
}